// Round 5
// baseline (269.128 us; speedup 1.0000x reference)
//
#include <hip/hip_runtime.h>
#include <math.h>

#define NTOT 8388608   // 2^23 = 32*4096*64
#define RR   2048      // n1 / k1 (column length, strided direction)
#define CC   4096      // n2 / k2 (row length, contiguous direction)
#define BB   32
#define LL   4096
#define DD   64

__device__ inline float2 cmul(float2 a, float2 b) {
    return make_float2(a.x*b.x - a.y*b.y, a.x*b.y + a.y*b.x);
}
__device__ inline float2 cmul_conj(float2 a, float2 b) {   // a * conj(b)
    return make_float2(a.x*b.x + a.y*b.y, a.y*b.x - a.x*b.y);
}
__device__ inline float2 cadd(float2 a, float2 b){ return make_float2(a.x+b.x, a.y+b.y); }
__device__ inline float2 csub(float2 a, float2 b){ return make_float2(a.x-b.x, a.y-b.y); }
__device__ inline float2 mul_pi(float2 a){ return make_float2(-a.y, a.x); }   // * i
__device__ inline float2 mul_mi(float2 a){ return make_float2(a.y, -a.x); }   // * -i
__device__ inline int pidx(int a){ return a + (a >> 4); }                     // pad (K2, 34KB)
__device__ inline int swz(int a){ return a ^ (((a >> 5) & 15) << 1); }        // 64KB col kernels

// DFT8: y_k = sum_m x_m W8^{+-km}
template<bool INV>
__device__ inline void dft8(const float2* x, float2* y) {
    const float C = 0.70710678118654752f;
    float2 t0=cadd(x[0],x[4]), t1=cadd(x[1],x[5]), t2=cadd(x[2],x[6]), t3=cadd(x[3],x[7]);
    float2 u0=csub(x[0],x[4]), u1=csub(x[1],x[5]), u2=csub(x[2],x[6]), u3=csub(x[3],x[7]);
    if (!INV) {
        u1 = make_float2(C*(u1.x+u1.y), C*(u1.y-u1.x));
        u2 = mul_mi(u2);
        u3 = make_float2(C*(u3.y-u3.x), -C*(u3.x+u3.y));
    } else {
        u1 = make_float2(C*(u1.x-u1.y), C*(u1.y+u1.x));
        u2 = mul_pi(u2);
        u3 = make_float2(-C*(u3.x+u3.y), C*(u3.x-u3.y));
    }
    {
        float2 s0=cadd(t0,t2), s1=cadd(t1,t3), d0=csub(t0,t2);
        float2 d1 = INV ? mul_pi(csub(t1,t3)) : mul_mi(csub(t1,t3));
        y[0]=cadd(s0,s1); y[4]=csub(s0,s1); y[2]=cadd(d0,d1); y[6]=csub(d0,d1);
    }
    {
        float2 s0=cadd(u0,u2), s1=cadd(u1,u3), d0=csub(u0,u2);
        float2 d1 = INV ? mul_pi(csub(u1,u3)) : mul_mi(csub(u1,u3));
        y[1]=cadd(s0,s1); y[5]=csub(s0,s1); y[3]=cadd(d0,d1); y[7]=csub(d0,d1);
    }
}

// inverse DFT8 with x[4..7] == 0 (Hilbert-zeroed upper half)
__device__ inline void dft8_h0_inv(const float2* x, float2* y) {
    const float C = 0.70710678118654752f;
    float2 u1 = make_float2(C*(x[1].x - x[1].y), C*(x[1].y + x[1].x));
    float2 u2 = mul_pi(x[2]);
    float2 u3 = make_float2(-C*(x[3].x + x[3].y), C*(x[3].x - x[3].y));
    {
        float2 s0=cadd(x[0],x[2]), s1=cadd(x[1],x[3]), d0=csub(x[0],x[2]);
        float2 d1 = mul_pi(csub(x[1],x[3]));
        y[0]=cadd(s0,s1); y[4]=csub(s0,s1); y[2]=cadd(d0,d1); y[6]=csub(d0,d1);
    }
    {
        float2 s0=cadd(x[0],u2), s1=cadd(u1,u3), d0=csub(x[0],u2);
        float2 d1 = mul_pi(csub(u1,u3));
        y[1]=cadd(s0,s1); y[5]=csub(s0,s1); y[3]=cadd(d0,d1); y[7]=csub(d0,d1);
    }
}

template<bool INV>
__device__ inline void dft4(const float2* u, float2* y) {
    float2 s0=cadd(u[0],u[2]), s1=cadd(u[1],u[3]), d0=csub(u[0],u[2]);
    float2 d1 = INV ? mul_pi(csub(u[1],u[3])) : mul_mi(csub(u[1],u[3]));
    y[0]=cadd(s0,s1); y[2]=csub(s0,s1); y[1]=cadd(d0,d1); y[3]=csub(d0,d1);
}

// y_k *= W^{+-ps*k}: ONE gather for w^1, powers via cmul tree
template<bool INV, int SH>
__device__ inline void twiddle8(float2* y, int ps, const float2* __restrict__ T1t) {
    float2 w1 = T1t[(ps << SH) & 4095];
    float2 w2 = cmul(w1, w1);
    float2 w3 = cmul(w2, w1);
    float2 w4 = cmul(w2, w2);
    float2 w5 = cmul(w4, w1);
    float2 w6 = cmul(w3, w3);
    float2 w7 = cmul(w4, w3);
    if (!INV) {
        y[1]=cmul(y[1],w1); y[2]=cmul(y[2],w2); y[3]=cmul(y[3],w3);
        y[4]=cmul(y[4],w4); y[5]=cmul(y[5],w5); y[6]=cmul(y[6],w6); y[7]=cmul(y[7],w7);
    } else {
        y[1]=cmul_conj(y[1],w1); y[2]=cmul_conj(y[2],w2); y[3]=cmul_conj(y[3],w3);
        y[4]=cmul_conj(y[4],w4); y[5]=cmul_conj(y[5],w5); y[6]=cmul_conj(y[6],w6); y[7]=cmul_conj(y[7],w7);
    }
}

// ---------------- twiddle tables ----------------
__global__ __launch_bounds__(256) void gen_tables(float2* T1, float2* T2) {
    int j = blockIdx.x * 256 + threadIdx.x;
    if (j < 4096) {
        double ang = -2.0 * M_PI * (double)j / 4096.0;
        T1[j] = make_float2((float)cos(ang), (float)sin(ang));
    } else if (j < 4096 + 2048) {
        int b = j - 4096;
        double ang = -2.0 * M_PI * (double)b / 8388608.0;
        T2[b] = make_float2((float)cos(ang), (float)sin(ang));
    }
}

__device__ inline float2 wbig(int t, const float2* __restrict__ T1t, const float2* __restrict__ T2t) {
    return cmul(T1t[t >> 11], T2t[t & 2047]);
}

// ---------------- K1: column FFT_2048 (fwd) + pack + four-step twiddle ----------------
// x viewed [RR=2048 rows n1][CC=4096 cols n2] (rows contiguous). Block: 4 columns.
// Y[k1][n2] = W_N^{n2 k1} * FFT_R_{n1}( up+i*down (x[n1][n2]) )
__global__ __launch_bounds__(256) void col_fwd(const float* __restrict__ x, float2* __restrict__ Y,
                                               const float2* __restrict__ T1t,
                                               const float2* __restrict__ T2t) {
    __shared__ float2 S[8192];   // exactly 64KB, XOR-swizzled
    const int t = threadIdx.x;
    const int c0 = blockIdx.x * 4;
    #pragma unroll
    for (int g = 0; g < 8; ++g) {
        int n1 = t + 256*g;
        float4 v = *(const float4*)(x + (size_t)n1*CC + c0);
        S[swz(4*n1+0)] = make_float2(fmaxf(v.x,0.f), fmaxf(-v.x,0.f));
        S[swz(4*n1+1)] = make_float2(fmaxf(v.y,0.f), fmaxf(-v.y,0.f));
        S[swz(4*n1+2)] = make_float2(fmaxf(v.z,0.f), fmaxf(-v.z,0.f));
        S[swz(4*n1+3)] = make_float2(fmaxf(v.w,0.f), fmaxf(-v.w,0.f));
    }
    __syncthreads();
    const int u = t >> 2, c = t & 3;
    const int n2 = c0 + c;
    float2 in[4][8], y[8];
    // radix-8 stages s=1,8,64 (256 butterfly ids, 4 groups/thread)
    #pragma unroll
    for (int st = 0; st < 3; ++st) {
        const int s = 1 << (3*st);
        #pragma unroll
        for (int g = 0; g < 4; ++g) {
            int j = u + 64*g;
            #pragma unroll
            for (int m = 0; m < 8; ++m) in[g][m] = S[swz(4*(j + 256*m) + c)];
        }
        __syncthreads();
        #pragma unroll
        for (int g = 0; g < 4; ++g) {
            int j = u + 64*g;
            int q = j & (s-1), ps = j - q;
            dft8<false>(in[g], y);
            twiddle8<false,1>(y, ps, T1t);
            #pragma unroll
            for (int k = 0; k < 8; ++k) S[swz(4*(8*ps + q + k*s) + c)] = y[k];
        }
        __syncthreads();
    }
    // final radix-4 (s=512) + four-step twiddle W_N^{n2*k1}
    float2 q4[8][4];
    #pragma unroll
    for (int g = 0; g < 8; ++g) {
        int j = u + 64*g;
        #pragma unroll
        for (int m = 0; m < 4; ++m) q4[g][m] = S[swz(4*(j + 512*m) + c)];
    }
    __syncthreads();
    const float2 ws = wbig(512 * n2, T1t, T2t);
    #pragma unroll
    for (int g = 0; g < 8; ++g) {
        int j = u + 64*g;
        float2 y4[4];
        dft4<false>(q4[g], y4);
        float2 wb = wbig(n2 * j, T1t, T2t);
        #pragma unroll
        for (int m = 0; m < 4; ++m) {
            S[swz(4*(j + 512*m) + c)] = cmul(y4[m], wb);
            wb = cmul(wb, ws);
        }
    }
    __syncthreads();
    // store rows k1: 4 cols = 32B chunk per row
    #pragma unroll
    for (int g = 0; g < 8; ++g) {
        int k1 = t + 256*g;
        float2 a = S[swz(4*k1+0)], b = S[swz(4*k1+1)];
        float2 cc2 = S[swz(4*k1+2)], d = S[swz(4*k1+3)];
        float4* p = (float4*)(Y + (size_t)k1*CC + c0);
        p[0] = make_float4(a.x, a.y, b.x, b.y);
        p[1] = make_float4(cc2.x, cc2.y, d.x, d.y);
    }
}

// ---------------- K2: contiguous rows: fwd FFT_4096 + H mask + inv FFT_4096 + conj twiddle/N ----------------
// row r = k1; element index = k2; global freq k = k2*2048 + k1
__global__ __launch_bounds__(512) void row_mid(float2* __restrict__ Y,
                                               const float2* __restrict__ T1t,
                                               const float2* __restrict__ T2t) {
    __shared__ float2 S[4352];
    const int t = threadIdx.x;
    const int r = blockIdx.x;
    float2* base = Y + (size_t)r * CC;
    float2 x8[8], y8[8];
    #pragma unroll
    for (int m = 0; m < 8; ++m) x8[m] = base[t + 512*m];
    // fwd stages s=1,8,64
    #pragma unroll
    for (int st = 0; st < 3; ++st) {
        const int s = 1 << (3*st);
        const int q = t & (s-1), ps = t - q;
        dft8<false>(x8, y8);
        twiddle8<false,0>(y8, ps, T1t);
        if (st) __syncthreads();
        #pragma unroll
        for (int k = 0; k < 8; ++k) S[pidx(8*ps + q + k*s)] = y8[k];
        __syncthreads();
        #pragma unroll
        for (int m = 0; m < 8; ++m) x8[m] = S[pidx(t + 512*m)];
    }
    // fwd final (s=512, ps=0) + mask + inverse stage0 (s=1, ps=t): all in registers
    dft8<false>(x8, y8);
    float2 z8[4];
    #pragma unroll
    for (int k = 0; k < 4; ++k) {           // k2 = t+512k < 2048 always
        int k2 = t + 512*k;
        float h = (k2 == 0 && r == 0) ? 1.f : 2.f;
        z8[k] = make_float2(y8[k].x*h, y8[k].y*h);
    }
    float2 corner = y8[4];                   // k2 = t+2048: survives only if t==0 && r==0
    dft8_h0_inv(z8, y8);
    if (r == 0 && t == 0) {
        #pragma unroll
        for (int k = 0; k < 8; ++k) {
            if (k & 1) { y8[k].x -= corner.x; y8[k].y -= corner.y; }
            else       { y8[k].x += corner.x; y8[k].y += corner.y; }
        }
    }
    twiddle8<true,0>(y8, t, T1t);
    __syncthreads();
    #pragma unroll
    for (int k = 0; k < 8; ++k) S[pidx(8*t + k)] = y8[k];
    __syncthreads();
    // inv stages s=8,64
    #pragma unroll
    for (int st = 1; st < 3; ++st) {
        const int s = 1 << (3*st);
        const int q = t & (s-1), ps = t - q;
        #pragma unroll
        for (int m = 0; m < 8; ++m) x8[m] = S[pidx(t + 512*m)];
        dft8<true>(x8, y8);
        twiddle8<true,0>(y8, ps, T1t);
        __syncthreads();
        #pragma unroll
        for (int k = 0; k < 8; ++k) S[pidx(8*ps + q + k*s)] = y8[k];
        __syncthreads();
    }
    // inv final + conj four-step twiddle * (1/N)
    #pragma unroll
    for (int m = 0; m < 8; ++m) x8[m] = S[pidx(t + 512*m)];
    dft8<true>(x8, y8);
    const float sc = 1.f / 8388608.f;
    float2 wb = wbig(r * t, T1t, T2t);
    wb.x *= sc; wb.y *= sc;
    const float2 wstep = wbig(512 * r, T1t, T2t);
    #pragma unroll
    for (int k = 0; k < 8; ++k) {
        base[t + 512*k] = cmul_conj(y8[k], wb);
        wb = cmul(wb, wstep);
    }
}

// ---------------- K3: column iFFT_2048 + envelope epilogue ----------------
__global__ __launch_bounds__(256) void col_inv(const float2* __restrict__ Y, const float* __restrict__ x,
                                               float* __restrict__ out,
                                               const float2* __restrict__ T1t,
                                               const float2* __restrict__ T2t) {
    __shared__ float2 S[8192];
    const int t = threadIdx.x;
    const int c0 = blockIdx.x * 4;
    #pragma unroll
    for (int g = 0; g < 8; ++g) {
        int k1 = t + 256*g;
        const float4* p = (const float4*)(Y + (size_t)k1*CC + c0);
        float4 ab = p[0], cd = p[1];
        S[swz(4*k1+0)] = make_float2(ab.x, ab.y);
        S[swz(4*k1+1)] = make_float2(ab.z, ab.w);
        S[swz(4*k1+2)] = make_float2(cd.x, cd.y);
        S[swz(4*k1+3)] = make_float2(cd.z, cd.w);
    }
    __syncthreads();
    const int u = t >> 2, c = t & 3;
    float2 in[4][8], y[8];
    #pragma unroll
    for (int st = 0; st < 3; ++st) {
        const int s = 1 << (3*st);
        #pragma unroll
        for (int g = 0; g < 4; ++g) {
            int j = u + 64*g;
            #pragma unroll
            for (int m = 0; m < 8; ++m) in[g][m] = S[swz(4*(j + 256*m) + c)];
        }
        __syncthreads();
        #pragma unroll
        for (int g = 0; g < 4; ++g) {
            int j = u + 64*g;
            int q = j & (s-1), ps = j - q;
            dft8<true>(in[g], y);
            twiddle8<true,1>(y, ps, T1t);
            #pragma unroll
            for (int k = 0; k < 8; ++k) S[swz(4*(8*ps + q + k*s) + c)] = y[k];
        }
        __syncthreads();
    }
    float2 q4[8][4];
    #pragma unroll
    for (int g = 0; g < 8; ++g) {
        int j = u + 64*g;
        #pragma unroll
        for (int m = 0; m < 4; ++m) q4[g][m] = S[swz(4*(j + 512*m) + c)];
    }
    __syncthreads();
    #pragma unroll
    for (int g = 0; g < 8; ++g) {
        int j = u + 64*g;
        float2 y4[4];
        dft4<true>(q4[g], y4);
        #pragma unroll
        for (int m = 0; m < 4; ++m) S[swz(4*(j + 512*m) + c)] = y4[m];
    }
    __syncthreads();
    // epilogue: envelope + imf + avg, 16B chunks
    #pragma unroll
    for (int g = 0; g < 8; ++g) {
        int n1 = t + 256*g;
        size_t n = (size_t)n1*CC + c0;
        float4 xv = *(const float4*)(x + n);
        float2 w0 = S[swz(4*n1+0)], w1 = S[swz(4*n1+1)];
        float2 w2 = S[swz(4*n1+2)], w3 = S[swz(4*n1+3)];
        float4 imf, avg;
        {
            float up, dn, hu, hd, em, en, a;
            up = fmaxf(xv.x,0.f); dn = fmaxf(-xv.x,0.f); hu = w0.y - dn; hd = up - w0.x;
            em = sqrtf(up*up+hu*hu); en = sqrtf(dn*dn+hd*hd); a = 0.5f*(em-en);
            imf.x = xv.x - a; avg.x = a;
            up = fmaxf(xv.y,0.f); dn = fmaxf(-xv.y,0.f); hu = w1.y - dn; hd = up - w1.x;
            em = sqrtf(up*up+hu*hu); en = sqrtf(dn*dn+hd*hd); a = 0.5f*(em-en);
            imf.y = xv.y - a; avg.y = a;
            up = fmaxf(xv.z,0.f); dn = fmaxf(-xv.z,0.f); hu = w2.y - dn; hd = up - w2.x;
            em = sqrtf(up*up+hu*hu); en = sqrtf(dn*dn+hd*hd); a = 0.5f*(em-en);
            imf.z = xv.z - a; avg.z = a;
            up = fmaxf(xv.w,0.f); dn = fmaxf(-xv.w,0.f); hu = w3.y - dn; hd = up - w3.x;
            em = sqrtf(up*up+hu*hu); en = sqrtf(dn*dn+hd*hd); a = 0.5f*(em-en);
            imf.w = xv.w - a; avg.w = a;
        }
        *(float4*)(out + n) = imf;
        *(float4*)(out + NTOT + n) = avg;
    }
}

// ---------------- std over L (ddof=1), then scale imf ----------------
__global__ __launch_bounds__(256) void std_partial(const float* __restrict__ imf, float* __restrict__ part) {
    int blk = blockIdx.x;
    int b   = blk >> 4;
    int ch  = blk & 15;
    int d   = threadIdx.x & 63;
    int lw  = threadIdx.x >> 6;
    float s1 = 0.f, s2 = 0.f;
    const float* base = imf + (size_t)b * LL * DD;
    for (int i = 0; i < 64; ++i) {
        int l = ch * 256 + lw * 64 + i;
        float v = base[(size_t)l * DD + d];
        s1 += v;
        s2 += v * v;
    }
    __shared__ float r1[4][64];
    __shared__ float r2[4][64];
    r1[lw][d] = s1; r2[lw][d] = s2;
    __syncthreads();
    if (lw == 0) {
        s1 = r1[0][d] + r1[1][d] + r1[2][d] + r1[3][d];
        s2 = r2[0][d] + r2[1][d] + r2[2][d] + r2[3][d];
        int pi = blk * 64 + d;
        part[pi] = s1;
        part[BB * 16 * 64 + pi] = s2;
    }
}

__global__ __launch_bounds__(256) void std_final(const float* __restrict__ part, float* __restrict__ scalev) {
    int g = blockIdx.x * 256 + threadIdx.x;
    int b = g >> 6, d = g & 63;
    float s1 = 0.f, s2 = 0.f;
    for (int ch = 0; ch < 16; ++ch) {
        int pi = (b * 16 + ch) * 64 + d;
        s1 += part[pi];
        s2 += part[BB * 16 * 64 + pi];
    }
    float mean = s1 / (float)LL;
    float var  = (s2 - (float)LL * mean * mean) / (float)(LL - 1);
    var = fmaxf(var, 0.f);
    scalev[g] = 1.f / (sqrtf(var) + 0.01f);
}

__global__ __launch_bounds__(256) void apply_scale(float* __restrict__ out, const float* __restrict__ scalev) {
    size_t i = ((size_t)blockIdx.x * 256 + threadIdx.x) * 4;
    float4 v = *(float4*)(out + i);
    int b = (int)(i >> 18);
    int d = (int)(i & 63);
    const float* sc = scalev + b * 64;
    v.x *= sc[d];
    v.y *= sc[d + 1];
    v.z *= sc[d + 2];
    v.w *= sc[d + 3];
    *(float4*)(out + i) = v;
}

// ---------------- launch ----------------
extern "C" void kernel_launch(void* const* d_in, const int* in_sizes, int n_in,
                              void* d_out, int out_size, void* d_ws, size_t ws_size,
                              hipStream_t stream) {
    const float* x = (const float*)d_in[0];
    float* out = (float*)d_out;
    char* w = (char*)d_ws;

    float2* T1     = (float2*)w;                   // 32 KB
    float2* T2     = (float2*)(w + 32 * 1024);     // 16 KB
    float*  part   = (float*)(w + 48 * 1024);      // 256 KB
    float*  scalev = (float*)(w + 320 * 1024);     // 8 KB
    float2* Y      = (float2*)(w + (1 << 20));     // 64 MB

    hipLaunchKernelGGL(gen_tables, dim3(24), dim3(256), 0, stream, T1, T2);

    hipLaunchKernelGGL(col_fwd, dim3(CC/4), dim3(256), 0, stream, x, Y, T1, T2);
    hipLaunchKernelGGL(row_mid, dim3(RR),   dim3(512), 0, stream, Y, T1, T2);
    hipLaunchKernelGGL(col_inv, dim3(CC/4), dim3(256), 0, stream, Y, x, out, T1, T2);

    hipLaunchKernelGGL(std_partial, dim3(BB * 16), dim3(256), 0, stream, out, part);
    hipLaunchKernelGGL(std_final, dim3(8), dim3(256), 0, stream, part, scalev);
    hipLaunchKernelGGL(apply_scale, dim3(NTOT / 4 / 256), dim3(256), 0, stream, out, scalev);
}

// Round 6
// 203.734 us; speedup vs baseline: 1.3210x; 1.3210x over previous
//
#include <hip/hip_runtime.h>
#include <math.h>

#define NTOT 8388608   // 2^23 = 32*4096*64
#define N1   2048
#define N2   4096
#define BB   32
#define LL   4096
#define DD   64

enum { M_NONE = 0, M_TW = 1, M_SCALE = 4 };

__device__ inline float2 cmul(float2 a, float2 b) {
    return make_float2(a.x*b.x - a.y*b.y, a.x*b.y + a.y*b.x);
}
__device__ inline float2 cmul_conj(float2 a, float2 b) {   // a * conj(b)
    return make_float2(a.x*b.x + a.y*b.y, a.y*b.x - a.x*b.y);
}
__device__ inline float2 cadd(float2 a, float2 b){ return make_float2(a.x+b.x, a.y+b.y); }
__device__ inline float2 csub(float2 a, float2 b){ return make_float2(a.x-b.x, a.y-b.y); }
__device__ inline float2 mul_pi(float2 a){ return make_float2(-a.y, a.x); }   // * i
__device__ inline float2 mul_mi(float2 a){ return make_float2(a.y, -a.x); }   // * -i
__device__ inline int pidx(int a){ return a + (a >> 4); }                     // float2 LDS pad

// DFT8: y_k = sum_m x_m W8^{+-km}
template<bool INV>
__device__ inline void dft8(const float2* x, float2* y) {
    const float C = 0.70710678118654752f;
    float2 t0=cadd(x[0],x[4]), t1=cadd(x[1],x[5]), t2=cadd(x[2],x[6]), t3=cadd(x[3],x[7]);
    float2 u0=csub(x[0],x[4]), u1=csub(x[1],x[5]), u2=csub(x[2],x[6]), u3=csub(x[3],x[7]);
    if (!INV) {
        u1 = make_float2(C*(u1.x+u1.y), C*(u1.y-u1.x));
        u2 = mul_mi(u2);
        u3 = make_float2(C*(u3.y-u3.x), -C*(u3.x+u3.y));
    } else {
        u1 = make_float2(C*(u1.x-u1.y), C*(u1.y+u1.x));
        u2 = mul_pi(u2);
        u3 = make_float2(-C*(u3.x+u3.y), C*(u3.x-u3.y));
    }
    {
        float2 s0=cadd(t0,t2), s1=cadd(t1,t3), d0=csub(t0,t2);
        float2 d1 = INV ? mul_pi(csub(t1,t3)) : mul_mi(csub(t1,t3));
        y[0]=cadd(s0,s1); y[4]=csub(s0,s1); y[2]=cadd(d0,d1); y[6]=csub(d0,d1);
    }
    {
        float2 s0=cadd(u0,u2), s1=cadd(u1,u3), d0=csub(u0,u2);
        float2 d1 = INV ? mul_pi(csub(u1,u3)) : mul_mi(csub(u1,u3));
        y[1]=cadd(s0,s1); y[5]=csub(s0,s1); y[3]=cadd(d0,d1); y[7]=csub(d0,d1);
    }
}

// inverse DFT8 with x[4..7] == 0 (Hilbert-zeroed upper half)
__device__ inline void dft8_h0_inv(const float2* x, float2* y) {
    const float C = 0.70710678118654752f;
    float2 u1 = make_float2(C*(x[1].x - x[1].y), C*(x[1].y + x[1].x));
    float2 u2 = mul_pi(x[2]);
    float2 u3 = make_float2(-C*(x[3].x + x[3].y), C*(x[3].x - x[3].y));
    {
        float2 s0=cadd(x[0],x[2]), s1=cadd(x[1],x[3]), d0=csub(x[0],x[2]);
        float2 d1 = mul_pi(csub(x[1],x[3]));
        y[0]=cadd(s0,s1); y[4]=csub(s0,s1); y[2]=cadd(d0,d1); y[6]=csub(d0,d1);
    }
    {
        float2 s0=cadd(x[0],u2), s1=cadd(u1,u3), d0=csub(x[0],u2);
        float2 d1 = mul_pi(csub(u1,u3));
        y[1]=cadd(s0,s1); y[5]=csub(s0,s1); y[3]=cadd(d0,d1); y[7]=csub(d0,d1);
    }
}

template<bool INV>
__device__ inline void dft4(const float2* u, float2* y) {
    float2 s0=cadd(u[0],u[2]), s1=cadd(u[1],u[3]), d0=csub(u[0],u[2]);
    float2 d1 = INV ? mul_pi(csub(u[1],u[3])) : mul_mi(csub(u[1],u[3]));
    y[0]=cadd(s0,s1); y[2]=csub(s0,s1); y[1]=cadd(d0,d1); y[3]=csub(d0,d1);
}

// y_k *= W^{+-ps*k}: ONE gather for w^1, powers via cmul tree (avoids divergent gathers)
template<bool INV, int SH>
__device__ inline void twiddle8(float2* y, int ps, const float2* __restrict__ T1t) {
    float2 w1 = T1t[(ps << SH) & 4095];
    float2 w2 = cmul(w1, w1);
    float2 w3 = cmul(w2, w1);
    float2 w4 = cmul(w2, w2);
    float2 w5 = cmul(w4, w1);
    float2 w6 = cmul(w3, w3);
    float2 w7 = cmul(w4, w3);
    if (!INV) {
        y[1]=cmul(y[1],w1); y[2]=cmul(y[2],w2); y[3]=cmul(y[3],w3);
        y[4]=cmul(y[4],w4); y[5]=cmul(y[5],w5); y[6]=cmul(y[6],w6); y[7]=cmul(y[7],w7);
    } else {
        y[1]=cmul_conj(y[1],w1); y[2]=cmul_conj(y[2],w2); y[3]=cmul_conj(y[3],w3);
        y[4]=cmul_conj(y[4],w4); y[5]=cmul_conj(y[5],w5); y[6]=cmul_conj(y[6],w6); y[7]=cmul_conj(y[7],w7);
    }
}

// ---------------- twiddle tables ----------------
__global__ __launch_bounds__(256) void gen_tables(float2* T1, float2* T2) {
    int j = blockIdx.x * 256 + threadIdx.x;
    if (j < 4096) {
        double ang = -2.0 * M_PI * (double)j / 4096.0;
        T1[j] = make_float2((float)cos(ang), (float)sin(ang));
    } else if (j < 4096 + 2048) {
        int b = j - 4096;
        double ang = -2.0 * M_PI * (double)b / 8388608.0;
        T2[b] = make_float2((float)cos(ang), (float)sin(ang));
    }
}

// W_2^23^{t} from split tables (t < 2^23)
__device__ inline float2 wbig(int t, const float2* __restrict__ T1t, const float2* __restrict__ T2t) {
    return cmul(T1t[t >> 11], T2t[t & 2047]);
}

// ---------------- 4096-point radix-8 Stockham, one row per block ----------------
template<bool INV, int MODE>
__global__ __launch_bounds__(512) void fft4096(float2* data,
                                               const float2* __restrict__ T1t,
                                               const float2* __restrict__ T2t) {
    __shared__ float2 S[4352];
    const int t = threadIdx.x;
    const int r = blockIdx.x;
    float2* base = data + (size_t)r * 4096;

    float2 x[8], y[8];
    #pragma unroll
    for (int m = 0; m < 8; ++m) x[m] = base[t + 512*m];

    #pragma unroll
    for (int st = 0; st < 3; ++st) {
        const int s = 1 << (3*st);
        const int q = t & (s - 1);
        const int ps = t - q;
        dft8<INV>(x, y);
        twiddle8<INV, 0>(y, ps, T1t);
        if (st) __syncthreads();
        #pragma unroll
        for (int k = 0; k < 8; ++k) S[pidx(8*ps + q + k*s)] = y[k];
        __syncthreads();
        #pragma unroll
        for (int m = 0; m < 8; ++m) x[m] = S[pidx(t + 512*m)];
    }
    dft8<INV>(x, y);

    if (MODE == M_TW) {
        float2 wb    = wbig(r * t, T1t, T2t);          // per-lane, 2 gathers total
        float2 wstep = wbig(512 * r, T1t, T2t);        // uniform
        #pragma unroll
        for (int k = 0; k < 8; ++k) {
            int o = t + 512*k;
            base[o] = INV ? cmul_conj(y[k], wb) : cmul(y[k], wb);
            wb = INV ? cmul_conj(wb, wstep) : cmul(wb, wstep);
        }
    } else {
        #pragma unroll
        for (int k = 0; k < 8; ++k) {
            int o = t + 512*k;
            float2 v = y[k];
            if (MODE == M_SCALE) {
                const float sc = 1.f / 8388608.f;
                v.x *= sc; v.y *= sc;
            }
            base[o] = v;
        }
    }
}

// ------- fused middle: fwd 2048 FFT + Hilbert mask + inv 2048 FFT + conj four-step twiddle -------
__global__ __launch_bounds__(256) void fftmid(float2* data,
                                              const float2* __restrict__ T1t,
                                              const float2* __restrict__ T2t) {
    __shared__ float2 S[2176];
    const int t = threadIdx.x;
    const int r = blockIdx.x;
    float2* base = data + (size_t)r * 2048;

    float2 x[8], y[8];
    #pragma unroll
    for (int m = 0; m < 8; ++m) x[m] = base[t + 256*m];

    #pragma unroll
    for (int st = 0; st < 3; ++st) {
        const int s = 1 << (3*st);
        const int q = t & (s - 1);
        const int ps = t - q;
        dft8<false>(x, y);
        twiddle8<false, 1>(y, ps, T1t);
        if (st) __syncthreads();
        #pragma unroll
        for (int k = 0; k < 8; ++k) S[pidx(8*ps + q + k*s)] = y[k];
        __syncthreads();
        if (st < 2) {
            #pragma unroll
            for (int m = 0; m < 8; ++m) x[m] = S[pidx(t + 256*m)];
        }
    }
    float2 xa[4], xb[4], ya[4], yb[4];
    #pragma unroll
    for (int m = 0; m < 4; ++m) {
        xa[m] = S[pidx(t + 512*m)];
        xb[m] = S[pidx(t + 256 + 512*m)];
    }
    dft4<false>(xa, ya);
    dft4<false>(xb, yb);
    __syncthreads();                           // WAR before mask writes
    #pragma unroll
    for (int k = 0; k < 4; ++k) {
        int o = t + 512*k;                     // global freq = o*N2 + r
        if (o < 1024) {
            float h = (o == 0 && r == 0) ? 1.f : 2.f;
            S[pidx(o)] = make_float2(ya[k].x * h, ya[k].y * h);
        } else if (o == 1024) {                // t==0, k==2
            S[pidx(1024)] = (r == 0) ? ya[k] : make_float2(0.f, 0.f);
        }
        int o2 = o + 256;                      // never 0 or 1024
        if (o2 < 1024) S[pidx(o2)] = make_float2(yb[k].x * 2.f, yb[k].y * 2.f);
    }
    __syncthreads();
    #pragma unroll
    for (int m = 0; m < 4; ++m) x[m] = S[pidx(t + 256*m)];
    dft8_h0_inv(x, y);
    if (t == 0) {                              // corner: freq o=1024 (h=1, r==0 only)
        float2 c = S[pidx(1024)];
        #pragma unroll
        for (int k = 0; k < 8; ++k) {
            if (k & 1) { y[k].x -= c.x; y[k].y -= c.y; }
            else       { y[k].x += c.x; y[k].y += c.y; }
        }
    }
    twiddle8<true, 1>(y, t, T1t);
    __syncthreads();                           // WAR vs masked reads
    #pragma unroll
    for (int k = 0; k < 8; ++k) S[pidx(8*t + k)] = y[k];
    __syncthreads();
    #pragma unroll
    for (int st = 1; st < 3; ++st) {
        const int s = 1 << (3*st);
        const int q = t & (s - 1);
        const int ps = t - q;
        #pragma unroll
        for (int m = 0; m < 8; ++m) x[m] = S[pidx(t + 256*m)];
        dft8<true>(x, y);
        twiddle8<true, 1>(y, ps, T1t);
        __syncthreads();
        #pragma unroll
        for (int k = 0; k < 8; ++k) S[pidx(8*ps + q + k*s)] = y[k];
        __syncthreads();
    }
    #pragma unroll
    for (int m = 0; m < 4; ++m) {
        xa[m] = S[pidx(t + 512*m)];
        xb[m] = S[pidx(t + 256 + 512*m)];
    }
    dft4<true>(xa, ya);
    dft4<true>(xb, yb);
    {
        float2 wka   = wbig(r * t, T1t, T2t);          // per-lane, 2 gathers
        float2 w256  = wbig(256 * r, T1t, T2t);        // uniform
        float2 w512  = cmul(w256, w256);               // uniform
        float2 wkb   = cmul(wka, w256);
        #pragma unroll
        for (int k = 0; k < 4; ++k) {
            int o = t + 512*k;
            base[o]       = cmul_conj(ya[k], wka);
            base[o + 256] = cmul_conj(yb[k], wkb);
            wka = cmul(wka, w512);
            wkb = cmul(wkb, w512);
        }
    }
}

// ---------------- transposes ----------------
__global__ __launch_bounds__(256) void k_pre(const float* __restrict__ x, float2* __restrict__ A) {
    __shared__ float tile[32][33];
    int c0 = blockIdx.x * 32;   // n1 tile
    int r0 = blockIdx.y * 32;   // n2 tile
    int tx = threadIdx.x, ty = threadIdx.y;
    #pragma unroll
    for (int j = 0; j < 32; j += 8)
        tile[ty + j][tx] = x[(size_t)(r0 + ty + j) * N1 + c0 + tx];
    __syncthreads();
    #pragma unroll
    for (int j = 0; j < 32; j += 8) {
        float v = tile[tx][ty + j];
        A[(size_t)(c0 + ty + j) * N2 + r0 + tx] = make_float2(fmaxf(v, 0.f), fmaxf(-v, 0.f));
    }
}

__global__ __launch_bounds__(256) void k_trans(const float2* __restrict__ in, float2* __restrict__ out,
                                               int inCols, int inRows) {
    __shared__ float2 tile[32][33];
    int c0 = blockIdx.x * 32;
    int r0 = blockIdx.y * 32;
    int tx = threadIdx.x, ty = threadIdx.y;
    #pragma unroll
    for (int j = 0; j < 32; j += 8)
        tile[ty + j][tx] = in[(size_t)(r0 + ty + j) * inCols + c0 + tx];
    __syncthreads();
    #pragma unroll
    for (int j = 0; j < 32; j += 8)
        out[(size_t)(c0 + ty + j) * inRows + r0 + tx] = tile[tx][ty + j];
}

// final transpose + envelope epilogue + deterministic std partials.
// Writes avg to out[NTOT..); writes per-block partial sums into part (the imf
// region of d_out, overwritten later by imf_final). No atomics.
__global__ __launch_bounds__(256) void k_post(const float2* __restrict__ A, const float* __restrict__ x,
                                              float* __restrict__ out, float* __restrict__ part) {
    __shared__ float2 tile[32][33];
    __shared__ float red[2][8][32];
    int c0 = blockIdx.x * 32;   // n2 tile
    int r0 = blockIdx.y * 32;   // n1 tile
    int tx = threadIdx.x, ty = threadIdx.y;
    #pragma unroll
    for (int j = 0; j < 32; j += 8)
        tile[ty + j][tx] = A[(size_t)(r0 + ty + j) * N2 + c0 + tx];
    __syncthreads();
    float s1 = 0.f, s2 = 0.f;
    #pragma unroll
    for (int j = 0; j < 32; j += 8) {
        int n2 = c0 + ty + j;
        int n1 = r0 + tx;
        size_t n = (size_t)n2 * N1 + n1;
        float2 w = tile[tx][ty + j];
        float xv = x[n];
        float up = fmaxf(xv, 0.f);
        float dn = fmaxf(-xv, 0.f);
        float hu = w.y - dn;          // H(up)
        float hd = up - w.x;          // H(down)
        float em = sqrtf(up*up + hu*hu);
        float en = sqrtf(dn*dn + hd*hd);
        float avg = 0.5f * (em - en);
        float imf = xv - avg;
        out[NTOT + n] = avg;
        s1 += imf;
        s2 += imf * imf;
    }
    red[0][ty][tx] = s1;
    red[1][ty][tx] = s2;
    __syncthreads();
    if (ty == 0) {
        #pragma unroll
        for (int e = 1; e < 8; ++e) { s1 += red[0][e][tx]; s2 += red[1][e][tx]; }
        int slot = blockIdx.y * 128 + blockIdx.x;   // 64*128 = 8192 slots
        part[slot * 32 + tx]          = s1;         // d = (blockIdx.y&1)*32 + tx
        part[262144 + slot * 32 + tx] = s2;
    }
}

// std over L (ddof=1) from k_post partials. g = b*64 + d, 2048 threads.
__global__ __launch_bounds__(256) void std_final(const float* __restrict__ part, float* __restrict__ scalev) {
    int g = blockIdx.x * 256 + threadIdx.x;
    int b = g >> 6, d = g & 63;
    int dh = d >> 5, dl = d & 31;
    float s1 = 0.f, s2 = 0.f;
    for (int lq = 0; lq < 32; ++lq) {
        int by = lq * 2 + dh;
        #pragma unroll
        for (int ch = 0; ch < 4; ++ch) {
            int slot = by * 128 + b * 4 + ch;
            s1 += part[slot * 32 + dl];
            s2 += part[262144 + slot * 32 + dl];
        }
    }
    float mean = s1 / (float)LL;
    float var  = (s2 - (float)LL * mean * mean) / (float)(LL - 1);
    var = fmaxf(var, 0.f);
    scalev[g] = 1.f / (sqrtf(var) + 0.01f);
}

// imf = (x - avg) * scale ; reads x + avg(out upper half), writes imf(out lower half)
__global__ __launch_bounds__(256) void imf_final(const float* __restrict__ x, float* __restrict__ out,
                                                 const float* __restrict__ scalev) {
    size_t i = ((size_t)blockIdx.x * 256 + threadIdx.x) * 4;
    float4 xv = *(const float4*)(x + i);
    float4 av = *(const float4*)(out + NTOT + i);
    int b = (int)(i >> 18);          // L*D = 2^18
    int d = (int)(i & 63);
    const float* sc = scalev + b * 64;
    float4 v;
    v.x = (xv.x - av.x) * sc[d];
    v.y = (xv.y - av.y) * sc[d + 1];
    v.z = (xv.z - av.z) * sc[d + 2];
    v.w = (xv.w - av.w) * sc[d + 3];
    *(float4*)(out + i) = v;
}

// ---------------- launch ----------------
extern "C" void kernel_launch(void* const* d_in, const int* in_sizes, int n_in,
                              void* d_out, int out_size, void* d_ws, size_t ws_size,
                              hipStream_t stream) {
    const float* x = (const float*)d_in[0];
    float* out = (float*)d_out;
    char* w = (char*)d_ws;

    float2* T1     = (float2*)w;                   // 32 KB
    float2* T2     = (float2*)(w + 32 * 1024);     // 16 KB
    float*  scalev = (float*)(w + 48 * 1024);      // 8 KB
    float2* A      = (float2*)(w + (1 << 20));     // 64 MB scratch
    float2* Bbuf   = (float2*)d_out;               // d_out doubles as 2nd 64 MB buffer
    float*  part   = (float*)d_out;                // 2 MB partials in imf region (free until imf_final)

    hipLaunchKernelGGL(gen_tables, dim3(24), dim3(256), 0, stream, T1, T2);

    hipLaunchKernelGGL(k_pre, dim3(N1/32, N2/32), dim3(32, 8), 0, stream, x, A);
    hipLaunchKernelGGL((fft4096<false, M_TW>), dim3(N1), dim3(512), 0, stream, A, T1, T2);
    hipLaunchKernelGGL(k_trans, dim3(N2/32, N1/32), dim3(32, 8), 0, stream, A, Bbuf, N2, N1);
    hipLaunchKernelGGL(fftmid, dim3(N2), dim3(256), 0, stream, Bbuf, T1, T2);
    hipLaunchKernelGGL(k_trans, dim3(N1/32, N2/32), dim3(32, 8), 0, stream, Bbuf, A, N1, N2);
    hipLaunchKernelGGL((fft4096<true, M_SCALE>), dim3(N1), dim3(512), 0, stream, A, T1, T2);

    // epilogue: envelope + avg + deterministic std partials, then scale pass
    hipLaunchKernelGGL(k_post, dim3(N2/32, N1/32), dim3(32, 8), 0, stream, A, x, out, part);
    hipLaunchKernelGGL(std_final, dim3(8), dim3(256), 0, stream, part, scalev);
    hipLaunchKernelGGL(imf_final, dim3(NTOT / 4 / 256), dim3(256), 0, stream, x, out, scalev);
}

// Round 7
// 200.083 us; speedup vs baseline: 1.3451x; 1.0182x over previous
//
#include <hip/hip_runtime.h>
#include <math.h>

#define NTOT 8388608   // 2^23 = 32*4096*64
#define N1   2048
#define N2   4096
#define BB   32
#define LL   4096
#define DD   64

enum { M_NONE = 0, M_TW = 1, M_SCALE = 4 };

__device__ inline float2 cmul(float2 a, float2 b) {
    return make_float2(a.x*b.x - a.y*b.y, a.x*b.y + a.y*b.x);
}
__device__ inline float2 cmul_conj(float2 a, float2 b) {   // a * conj(b)
    return make_float2(a.x*b.x + a.y*b.y, a.y*b.x - a.x*b.y);
}
__device__ inline float2 cadd(float2 a, float2 b){ return make_float2(a.x+b.x, a.y+b.y); }
__device__ inline float2 csub(float2 a, float2 b){ return make_float2(a.x-b.x, a.y-b.y); }
__device__ inline float2 mul_pi(float2 a){ return make_float2(-a.y, a.x); }   // * i
__device__ inline float2 mul_mi(float2 a){ return make_float2(a.y, -a.x); }   // * -i
__device__ inline int pidx(int a){ return a + (a >> 4); }                     // float2 LDS pad

// DFT8: y_k = sum_m x_m W8^{+-km}
template<bool INV>
__device__ inline void dft8(const float2* x, float2* y) {
    const float C = 0.70710678118654752f;
    float2 t0=cadd(x[0],x[4]), t1=cadd(x[1],x[5]), t2=cadd(x[2],x[6]), t3=cadd(x[3],x[7]);
    float2 u0=csub(x[0],x[4]), u1=csub(x[1],x[5]), u2=csub(x[2],x[6]), u3=csub(x[3],x[7]);
    if (!INV) {
        u1 = make_float2(C*(u1.x+u1.y), C*(u1.y-u1.x));
        u2 = mul_mi(u2);
        u3 = make_float2(C*(u3.y-u3.x), -C*(u3.x+u3.y));
    } else {
        u1 = make_float2(C*(u1.x-u1.y), C*(u1.y+u1.x));
        u2 = mul_pi(u2);
        u3 = make_float2(-C*(u3.x+u3.y), C*(u3.x-u3.y));
    }
    {
        float2 s0=cadd(t0,t2), s1=cadd(t1,t3), d0=csub(t0,t2);
        float2 d1 = INV ? mul_pi(csub(t1,t3)) : mul_mi(csub(t1,t3));
        y[0]=cadd(s0,s1); y[4]=csub(s0,s1); y[2]=cadd(d0,d1); y[6]=csub(d0,d1);
    }
    {
        float2 s0=cadd(u0,u2), s1=cadd(u1,u3), d0=csub(u0,u2);
        float2 d1 = INV ? mul_pi(csub(u1,u3)) : mul_mi(csub(u1,u3));
        y[1]=cadd(s0,s1); y[5]=csub(s0,s1); y[3]=cadd(d0,d1); y[7]=csub(d0,d1);
    }
}

// inverse DFT8 with x[4..7] == 0 (Hilbert-zeroed upper half)
__device__ inline void dft8_h0_inv(const float2* x, float2* y) {
    const float C = 0.70710678118654752f;
    float2 u1 = make_float2(C*(x[1].x - x[1].y), C*(x[1].y + x[1].x));
    float2 u2 = mul_pi(x[2]);
    float2 u3 = make_float2(-C*(x[3].x + x[3].y), C*(x[3].x - x[3].y));
    {
        float2 s0=cadd(x[0],x[2]), s1=cadd(x[1],x[3]), d0=csub(x[0],x[2]);
        float2 d1 = mul_pi(csub(x[1],x[3]));
        y[0]=cadd(s0,s1); y[4]=csub(s0,s1); y[2]=cadd(d0,d1); y[6]=csub(d0,d1);
    }
    {
        float2 s0=cadd(x[0],u2), s1=cadd(u1,u3), d0=csub(x[0],u2);
        float2 d1 = mul_pi(csub(u1,u3));
        y[1]=cadd(s0,s1); y[5]=csub(s0,s1); y[3]=cadd(d0,d1); y[7]=csub(d0,d1);
    }
}

template<bool INV>
__device__ inline void dft4(const float2* u, float2* y) {
    float2 s0=cadd(u[0],u[2]), s1=cadd(u[1],u[3]), d0=csub(u[0],u[2]);
    float2 d1 = INV ? mul_pi(csub(u[1],u[3])) : mul_mi(csub(u[1],u[3]));
    y[0]=cadd(s0,s1); y[2]=csub(s0,s1); y[1]=cadd(d0,d1); y[3]=csub(d0,d1);
}

// y_k *= W^{+-ps*k}: ONE gather for w^1, powers via cmul tree (avoids divergent gathers)
template<bool INV, int SH>
__device__ inline void twiddle8(float2* y, int ps, const float2* __restrict__ T1t) {
    float2 w1 = T1t[(ps << SH) & 4095];
    float2 w2 = cmul(w1, w1);
    float2 w3 = cmul(w2, w1);
    float2 w4 = cmul(w2, w2);
    float2 w5 = cmul(w4, w1);
    float2 w6 = cmul(w3, w3);
    float2 w7 = cmul(w4, w3);
    if (!INV) {
        y[1]=cmul(y[1],w1); y[2]=cmul(y[2],w2); y[3]=cmul(y[3],w3);
        y[4]=cmul(y[4],w4); y[5]=cmul(y[5],w5); y[6]=cmul(y[6],w6); y[7]=cmul(y[7],w7);
    } else {
        y[1]=cmul_conj(y[1],w1); y[2]=cmul_conj(y[2],w2); y[3]=cmul_conj(y[3],w3);
        y[4]=cmul_conj(y[4],w4); y[5]=cmul_conj(y[5],w5); y[6]=cmul_conj(y[6],w6); y[7]=cmul_conj(y[7],w7);
    }
}

// W_2^23^{t} from split tables (t < 2^23)
__device__ inline float2 wbig(int t, const float2* __restrict__ T1t, const float2* __restrict__ T2t) {
    return cmul(T1t[t >> 11], T2t[t & 2047]);
}

// ---------------- 4096-point radix-8 Stockham, one row per block ----------------
template<bool INV, int MODE>
__global__ __launch_bounds__(512) void fft4096(float2* data,
                                               const float2* __restrict__ T1t,
                                               const float2* __restrict__ T2t) {
    __shared__ float2 S[4352];
    const int t = threadIdx.x;
    const int r = blockIdx.x;
    float2* base = data + (size_t)r * 4096;

    float2 x[8], y[8];
    #pragma unroll
    for (int m = 0; m < 8; ++m) x[m] = base[t + 512*m];

    #pragma unroll
    for (int st = 0; st < 3; ++st) {
        const int s = 1 << (3*st);
        const int q = t & (s - 1);
        const int ps = t - q;
        dft8<INV>(x, y);
        twiddle8<INV, 0>(y, ps, T1t);
        if (st) __syncthreads();
        #pragma unroll
        for (int k = 0; k < 8; ++k) S[pidx(8*ps + q + k*s)] = y[k];
        __syncthreads();
        #pragma unroll
        for (int m = 0; m < 8; ++m) x[m] = S[pidx(t + 512*m)];
    }
    dft8<INV>(x, y);

    if (MODE == M_TW) {
        float2 wb    = wbig(r * t, T1t, T2t);          // per-lane, 2 gathers total
        float2 wstep = wbig(512 * r, T1t, T2t);        // uniform
        #pragma unroll
        for (int k = 0; k < 8; ++k) {
            int o = t + 512*k;
            base[o] = INV ? cmul_conj(y[k], wb) : cmul(y[k], wb);
            wb = INV ? cmul_conj(wb, wstep) : cmul(wb, wstep);
        }
    } else {
        #pragma unroll
        for (int k = 0; k < 8; ++k) {
            int o = t + 512*k;
            float2 v = y[k];
            if (MODE == M_SCALE) {
                const float sc = 1.f / 8388608.f;
                v.x *= sc; v.y *= sc;
            }
            base[o] = v;
        }
    }
}

// ------- fused middle: fwd 2048 FFT + Hilbert mask + inv 2048 FFT + conj four-step twiddle -------
// TWO rows per block (512 threads); r4-final + mask + inv-stage-0 fused in registers.
__global__ __launch_bounds__(512) void fftmid(float2* data,
                                              const float2* __restrict__ T1t,
                                              const float2* __restrict__ T2t) {
    __shared__ float2 S2[2][2176];
    const int t    = threadIdx.x & 255;
    const int half = threadIdx.x >> 8;
    const int r    = (blockIdx.x << 1) | half;
    float2* S = S2[half];
    float2* base = data + (size_t)r * 2048;

    float2 x[8], y[8];
    #pragma unroll
    for (int m = 0; m < 8; ++m) x[m] = base[t + 256*m];

    // ---- forward: radix-8 stages s=1,8,64 ----
    #pragma unroll
    for (int st = 0; st < 3; ++st) {
        const int s = 1 << (3*st);
        const int q = t & (s - 1);
        const int ps = t - q;
        dft8<false>(x, y);
        twiddle8<false, 1>(y, ps, T1t);
        if (st) __syncthreads();
        #pragma unroll
        for (int k = 0; k < 8; ++k) S[pidx(8*ps + q + k*s)] = y[k];
        __syncthreads();
        if (st < 2) {
            #pragma unroll
            for (int m = 0; m < 8; ++m) x[m] = S[pidx(t + 256*m)];
        }
    }
    // ---- fwd final radix-4 (s=512, ps=0) + Hilbert mask + inv stage-0: all in registers ----
    // thread t's two r4 butterflies produce positions {t+512k} и {t+256+512k} =
    // exactly {t+256m, m=0..7} = the input set of its inverse radix-8 butterfly.
    float2 xa[4], xb[4], ya[4], yb[4];
    #pragma unroll
    for (int m = 0; m < 4; ++m) {
        xa[m] = S[pidx(t + 512*m)];
        xb[m] = S[pidx(t + 256 + 512*m)];
    }
    dft4<false>(xa, ya);   // positions o = t + 512k
    dft4<false>(xb, yb);   // positions o = t + 256 + 512k
    {
        float2 z[4];
        float h0 = (t == 0 && r == 0) ? 1.f : 2.f;          // o = t (global k = t*4096+r)
        z[0] = make_float2(ya[0].x * h0, ya[0].y * h0);     // o = t      (<1024)
        z[1] = make_float2(yb[0].x * 2.f, yb[0].y * 2.f);   // o = t+256  (<1024)
        z[2] = make_float2(ya[1].x * 2.f, ya[1].y * 2.f);   // o = t+512  (<1024)
        z[3] = make_float2(yb[1].x * 2.f, yb[1].y * 2.f);   // o = t+768  (<1024)
        dft8_h0_inv(z, y);
        if (t == 0 && r == 0) {                             // corner o=1024 (h=1): ya[2]
            float2 c = ya[2];
            #pragma unroll
            for (int k = 0; k < 8; ++k) {
                if (k & 1) { y[k].x -= c.x; y[k].y -= c.y; }
                else       { y[k].x += c.x; y[k].y += c.y; }
            }
        }
    }
    twiddle8<true, 1>(y, t, T1t);
    __syncthreads();                           // WAR: all r4 reads done before overwrite
    #pragma unroll
    for (int k = 0; k < 8; ++k) S[pidx(8*t + k)] = y[k];
    __syncthreads();
    // ---- inv stages s=8,64 ----
    #pragma unroll
    for (int st = 1; st < 3; ++st) {
        const int s = 1 << (3*st);
        const int q = t & (s - 1);
        const int ps = t - q;
        #pragma unroll
        for (int m = 0; m < 8; ++m) x[m] = S[pidx(t + 256*m)];
        dft8<true>(x, y);
        twiddle8<true, 1>(y, ps, T1t);
        __syncthreads();
        #pragma unroll
        for (int k = 0; k < 8; ++k) S[pidx(8*ps + q + k*s)] = y[k];
        __syncthreads();
    }
    // ---- inverse final radix-4 + conj four-step twiddle + store ----
    #pragma unroll
    for (int m = 0; m < 4; ++m) {
        xa[m] = S[pidx(t + 512*m)];
        xb[m] = S[pidx(t + 256 + 512*m)];
    }
    dft4<true>(xa, ya);
    dft4<true>(xb, yb);
    {
        float2 wka   = wbig(r * t, T1t, T2t);          // per-lane, 2 gathers
        float2 w256  = wbig(256 * r, T1t, T2t);        // uniform
        float2 w512  = cmul(w256, w256);               // uniform
        float2 wkb   = cmul(wka, w256);
        #pragma unroll
        for (int k = 0; k < 4; ++k) {
            int o = t + 512*k;
            base[o]       = cmul_conj(ya[k], wka);
            base[o + 256] = cmul_conj(yb[k], wkb);
            wka = cmul(wka, w512);
            wkb = cmul(wkb, w512);
        }
    }
}

// ---------------- transposes ----------------
// k_pre also generates the twiddle tables in its first 24 (y==0) blocks.
__global__ __launch_bounds__(256) void k_pre(const float* __restrict__ x, float2* __restrict__ A,
                                             float2* T1, float2* T2) {
    __shared__ float tile[32][33];
    int c0 = blockIdx.x * 32;   // n1 tile
    int r0 = blockIdx.y * 32;   // n2 tile
    int tx = threadIdx.x, ty = threadIdx.y;
    if (blockIdx.y == 0 && blockIdx.x < 24) {
        int j = blockIdx.x * 256 + ty * 32 + tx;
        if (j < 4096) {
            double ang = -2.0 * M_PI * (double)j / 4096.0;
            T1[j] = make_float2((float)cos(ang), (float)sin(ang));
        } else if (j < 4096 + 2048) {
            int b = j - 4096;
            double ang = -2.0 * M_PI * (double)b / 8388608.0;
            T2[b] = make_float2((float)cos(ang), (float)sin(ang));
        }
    }
    #pragma unroll
    for (int j = 0; j < 32; j += 8)
        tile[ty + j][tx] = x[(size_t)(r0 + ty + j) * N1 + c0 + tx];
    __syncthreads();
    #pragma unroll
    for (int j = 0; j < 32; j += 8) {
        float v = tile[tx][ty + j];
        A[(size_t)(c0 + ty + j) * N2 + r0 + tx] = make_float2(fmaxf(v, 0.f), fmaxf(-v, 0.f));
    }
}

__global__ __launch_bounds__(256) void k_trans(const float2* __restrict__ in, float2* __restrict__ out,
                                               int inCols, int inRows) {
    __shared__ float2 tile[32][33];
    int c0 = blockIdx.x * 32;
    int r0 = blockIdx.y * 32;
    int tx = threadIdx.x, ty = threadIdx.y;
    #pragma unroll
    for (int j = 0; j < 32; j += 8)
        tile[ty + j][tx] = in[(size_t)(r0 + ty + j) * inCols + c0 + tx];
    __syncthreads();
    #pragma unroll
    for (int j = 0; j < 32; j += 8)
        out[(size_t)(c0 + ty + j) * inRows + r0 + tx] = tile[tx][ty + j];
}

// final transpose + envelope epilogue + deterministic std partials.
__global__ __launch_bounds__(256) void k_post(const float2* __restrict__ A, const float* __restrict__ x,
                                              float* __restrict__ out, float* __restrict__ part) {
    __shared__ float2 tile[32][33];
    __shared__ float red[2][8][32];
    int c0 = blockIdx.x * 32;   // n2 tile
    int r0 = blockIdx.y * 32;   // n1 tile
    int tx = threadIdx.x, ty = threadIdx.y;
    #pragma unroll
    for (int j = 0; j < 32; j += 8)
        tile[ty + j][tx] = A[(size_t)(r0 + ty + j) * N2 + c0 + tx];
    __syncthreads();
    float s1 = 0.f, s2 = 0.f;
    #pragma unroll
    for (int j = 0; j < 32; j += 8) {
        int n2 = c0 + ty + j;
        int n1 = r0 + tx;
        size_t n = (size_t)n2 * N1 + n1;
        float2 w = tile[tx][ty + j];
        float xv = x[n];
        float up = fmaxf(xv, 0.f);
        float dn = fmaxf(-xv, 0.f);
        float hu = w.y - dn;          // H(up)
        float hd = up - w.x;          // H(down)
        float em = sqrtf(up*up + hu*hu);
        float en = sqrtf(dn*dn + hd*hd);
        float avg = 0.5f * (em - en);
        float imf = xv - avg;
        out[NTOT + n] = avg;
        s1 += imf;
        s2 += imf * imf;
    }
    red[0][ty][tx] = s1;
    red[1][ty][tx] = s2;
    __syncthreads();
    if (ty == 0) {
        #pragma unroll
        for (int e = 1; e < 8; ++e) { s1 += red[0][e][tx]; s2 += red[1][e][tx]; }
        int slot = blockIdx.y * 128 + blockIdx.x;   // 64*128 = 8192 slots
        part[slot * 32 + tx]          = s1;
        part[262144 + slot * 32 + tx] = s2;
    }
}

// std over L (ddof=1) from k_post partials. g = b*64 + d, 2048 threads.
__global__ __launch_bounds__(256) void std_final(const float* __restrict__ part, float* __restrict__ scalev) {
    int g = blockIdx.x * 256 + threadIdx.x;
    int b = g >> 6, d = g & 63;
    int dh = d >> 5, dl = d & 31;
    float s1 = 0.f, s2 = 0.f;
    for (int lq = 0; lq < 32; ++lq) {
        int by = lq * 2 + dh;
        #pragma unroll
        for (int ch = 0; ch < 4; ++ch) {
            int slot = by * 128 + b * 4 + ch;
            s1 += part[slot * 32 + dl];
            s2 += part[262144 + slot * 32 + dl];
        }
    }
    float mean = s1 / (float)LL;
    float var  = (s2 - (float)LL * mean * mean) / (float)(LL - 1);
    var = fmaxf(var, 0.f);
    scalev[g] = 1.f / (sqrtf(var) + 0.01f);
}

// imf = (x - avg) * scale
__global__ __launch_bounds__(256) void imf_final(const float* __restrict__ x, float* __restrict__ out,
                                                 const float* __restrict__ scalev) {
    size_t i = ((size_t)blockIdx.x * 256 + threadIdx.x) * 4;
    float4 xv = *(const float4*)(x + i);
    float4 av = *(const float4*)(out + NTOT + i);
    int b = (int)(i >> 18);          // L*D = 2^18
    int d = (int)(i & 63);
    const float* sc = scalev + b * 64;
    float4 v;
    v.x = (xv.x - av.x) * sc[d];
    v.y = (xv.y - av.y) * sc[d + 1];
    v.z = (xv.z - av.z) * sc[d + 2];
    v.w = (xv.w - av.w) * sc[d + 3];
    *(float4*)(out + i) = v;
}

// ---------------- launch ----------------
extern "C" void kernel_launch(void* const* d_in, const int* in_sizes, int n_in,
                              void* d_out, int out_size, void* d_ws, size_t ws_size,
                              hipStream_t stream) {
    const float* x = (const float*)d_in[0];
    float* out = (float*)d_out;
    char* w = (char*)d_ws;

    float2* T1     = (float2*)w;                   // 32 KB
    float2* T2     = (float2*)(w + 32 * 1024);     // 16 KB
    float*  scalev = (float*)(w + 48 * 1024);      // 8 KB
    float2* A      = (float2*)(w + (1 << 20));     // 64 MB scratch
    float2* Bbuf   = (float2*)d_out;               // d_out doubles as 2nd 64 MB buffer
    float*  part   = (float*)d_out;                // 2 MB partials in imf region (free until imf_final)

    hipLaunchKernelGGL(k_pre, dim3(N1/32, N2/32), dim3(32, 8), 0, stream, x, A, T1, T2);
    hipLaunchKernelGGL((fft4096<false, M_TW>), dim3(N1), dim3(512), 0, stream, A, T1, T2);
    hipLaunchKernelGGL(k_trans, dim3(N2/32, N1/32), dim3(32, 8), 0, stream, A, Bbuf, N2, N1);
    hipLaunchKernelGGL(fftmid, dim3(N2/2), dim3(512), 0, stream, Bbuf, T1, T2);
    hipLaunchKernelGGL(k_trans, dim3(N1/32, N2/32), dim3(32, 8), 0, stream, Bbuf, A, N1, N2);
    hipLaunchKernelGGL((fft4096<true, M_SCALE>), dim3(N1), dim3(512), 0, stream, A, T1, T2);

    hipLaunchKernelGGL(k_post, dim3(N2/32, N1/32), dim3(32, 8), 0, stream, A, x, out, part);
    hipLaunchKernelGGL(std_final, dim3(8), dim3(256), 0, stream, part, scalev);
    hipLaunchKernelGGL(imf_final, dim3(NTOT / 4 / 256), dim3(256), 0, stream, x, out, scalev);
}

// Round 8
// 197.575 us; speedup vs baseline: 1.3622x; 1.0127x over previous
//
#include <hip/hip_runtime.h>
#include <math.h>

#define NTOT 8388608   // 2^23 = 32*4096*64
#define N1   2048
#define N2   4096
#define BB   32
#define LL   4096
#define DD   64

enum { M_NONE = 0, M_TW = 1, M_SCALE = 4 };

__device__ inline float2 cmul(float2 a, float2 b) {
    return make_float2(a.x*b.x - a.y*b.y, a.x*b.y + a.y*b.x);
}
__device__ inline float2 cmul_conj(float2 a, float2 b) {   // a * conj(b)
    return make_float2(a.x*b.x + a.y*b.y, a.y*b.x - a.x*b.y);
}
__device__ inline float2 cadd(float2 a, float2 b){ return make_float2(a.x+b.x, a.y+b.y); }
__device__ inline float2 csub(float2 a, float2 b){ return make_float2(a.x-b.x, a.y-b.y); }
__device__ inline float2 mul_pi(float2 a){ return make_float2(-a.y, a.x); }   // * i
__device__ inline float2 mul_mi(float2 a){ return make_float2(a.y, -a.x); }   // * -i
__device__ inline int pidx(int a){ return a + (a >> 4); }                     // float2 LDS pad

// DFT8: y_k = sum_m x_m W8^{+-km}
template<bool INV>
__device__ inline void dft8(const float2* x, float2* y) {
    const float C = 0.70710678118654752f;
    float2 t0=cadd(x[0],x[4]), t1=cadd(x[1],x[5]), t2=cadd(x[2],x[6]), t3=cadd(x[3],x[7]);
    float2 u0=csub(x[0],x[4]), u1=csub(x[1],x[5]), u2=csub(x[2],x[6]), u3=csub(x[3],x[7]);
    if (!INV) {
        u1 = make_float2(C*(u1.x+u1.y), C*(u1.y-u1.x));
        u2 = mul_mi(u2);
        u3 = make_float2(C*(u3.y-u3.x), -C*(u3.x+u3.y));
    } else {
        u1 = make_float2(C*(u1.x-u1.y), C*(u1.y+u1.x));
        u2 = mul_pi(u2);
        u3 = make_float2(-C*(u3.x+u3.y), C*(u3.x-u3.y));
    }
    {
        float2 s0=cadd(t0,t2), s1=cadd(t1,t3), d0=csub(t0,t2);
        float2 d1 = INV ? mul_pi(csub(t1,t3)) : mul_mi(csub(t1,t3));
        y[0]=cadd(s0,s1); y[4]=csub(s0,s1); y[2]=cadd(d0,d1); y[6]=csub(d0,d1);
    }
    {
        float2 s0=cadd(u0,u2), s1=cadd(u1,u3), d0=csub(u0,u2);
        float2 d1 = INV ? mul_pi(csub(u1,u3)) : mul_mi(csub(u1,u3));
        y[1]=cadd(s0,s1); y[5]=csub(s0,s1); y[3]=cadd(d0,d1); y[7]=csub(d0,d1);
    }
}

// DFT16 = split into even/odd DFT8 + W16^k combine
template<bool INV>
__device__ inline void dft16(const float2* x, float2* y) {
    const float C  = 0.70710678118654752f;
    const float c1 = 0.92387953251128674f;   // cos(pi/8)
    const float s1 = 0.38268343236508977f;   // sin(pi/8)
    float2 e[8], o[8], E[8], O[8];
    #pragma unroll
    for (int m = 0; m < 8; ++m) { e[m] = x[2*m]; o[m] = x[2*m+1]; }
    dft8<INV>(e, E);
    dft8<INV>(o, O);
    // O[k] *= W16^{+-k}
    O[1] = cmul(O[1], make_float2( c1, INV ?  s1 : -s1));
    O[2] = cmul(O[2], make_float2(  C, INV ?   C : -C ));
    O[3] = cmul(O[3], make_float2( s1, INV ?  c1 : -c1));
    O[4] = INV ? mul_pi(O[4]) : mul_mi(O[4]);
    O[5] = cmul(O[5], make_float2(-s1, INV ?  c1 : -c1));
    O[6] = cmul(O[6], make_float2( -C, INV ?   C : -C ));
    O[7] = cmul(O[7], make_float2(-c1, INV ?  s1 : -s1));
    #pragma unroll
    for (int k = 0; k < 8; ++k) {
        y[k]     = cadd(E[k], O[k]);
        y[k + 8] = csub(E[k], O[k]);
    }
}

// inverse DFT8 with x[4..7] == 0 (Hilbert-zeroed upper half)
__device__ inline void dft8_h0_inv(const float2* x, float2* y) {
    const float C = 0.70710678118654752f;
    float2 u1 = make_float2(C*(x[1].x - x[1].y), C*(x[1].y + x[1].x));
    float2 u2 = mul_pi(x[2]);
    float2 u3 = make_float2(-C*(x[3].x + x[3].y), C*(x[3].x - x[3].y));
    {
        float2 s0=cadd(x[0],x[2]), s1=cadd(x[1],x[3]), d0=csub(x[0],x[2]);
        float2 d1 = mul_pi(csub(x[1],x[3]));
        y[0]=cadd(s0,s1); y[4]=csub(s0,s1); y[2]=cadd(d0,d1); y[6]=csub(d0,d1);
    }
    {
        float2 s0=cadd(x[0],u2), s1=cadd(u1,u3), d0=csub(x[0],u2);
        float2 d1 = mul_pi(csub(u1,u3));
        y[1]=cadd(s0,s1); y[5]=csub(s0,s1); y[3]=cadd(d0,d1); y[7]=csub(d0,d1);
    }
}

template<bool INV>
__device__ inline void dft4(const float2* u, float2* y) {
    float2 s0=cadd(u[0],u[2]), s1=cadd(u[1],u[3]), d0=csub(u[0],u[2]);
    float2 d1 = INV ? mul_pi(csub(u[1],u[3])) : mul_mi(csub(u[1],u[3]));
    y[0]=cadd(s0,s1); y[2]=csub(s0,s1); y[1]=cadd(d0,d1); y[3]=csub(d0,d1);
}

// y_k *= W^{+-ps*k}, k=1..7: ONE gather + cmul power tree
template<bool INV, int SH>
__device__ inline void twiddle8(float2* y, int ps, const float2* __restrict__ T1t) {
    float2 w1 = T1t[(ps << SH) & 4095];
    float2 w2 = cmul(w1, w1);
    float2 w3 = cmul(w2, w1);
    float2 w4 = cmul(w2, w2);
    float2 w5 = cmul(w4, w1);
    float2 w6 = cmul(w3, w3);
    float2 w7 = cmul(w4, w3);
    if (!INV) {
        y[1]=cmul(y[1],w1); y[2]=cmul(y[2],w2); y[3]=cmul(y[3],w3);
        y[4]=cmul(y[4],w4); y[5]=cmul(y[5],w5); y[6]=cmul(y[6],w6); y[7]=cmul(y[7],w7);
    } else {
        y[1]=cmul_conj(y[1],w1); y[2]=cmul_conj(y[2],w2); y[3]=cmul_conj(y[3],w3);
        y[4]=cmul_conj(y[4],w4); y[5]=cmul_conj(y[5],w5); y[6]=cmul_conj(y[6],w6); y[7]=cmul_conj(y[7],w7);
    }
}

// y_k *= W_4096^{+-ps*k}, k=1..15
template<bool INV>
__device__ inline void twiddle16(float2* y, int ps, const float2* __restrict__ T1t) {
    float2 w[16];
    w[1] = T1t[ps & 4095];
    w[2] = cmul(w[1], w[1]);
    w[3] = cmul(w[2], w[1]);
    w[4] = cmul(w[2], w[2]);
    w[5] = cmul(w[4], w[1]);
    w[6] = cmul(w[3], w[3]);
    w[7] = cmul(w[4], w[3]);
    w[8] = cmul(w[4], w[4]);
    w[9] = cmul(w[8], w[1]);
    w[10]= cmul(w[5], w[5]);
    w[11]= cmul(w[8], w[3]);
    w[12]= cmul(w[6], w[6]);
    w[13]= cmul(w[8], w[5]);
    w[14]= cmul(w[7], w[7]);
    w[15]= cmul(w[8], w[7]);
    #pragma unroll
    for (int k = 1; k < 16; ++k)
        y[k] = INV ? cmul_conj(y[k], w[k]) : cmul(y[k], w[k]);
}

// W_2^23^{t} from split tables (t < 2^23)
__device__ inline float2 wbig(int t, const float2* __restrict__ T1t, const float2* __restrict__ T2t) {
    return cmul(T1t[t >> 11], T2t[t & 2047]);
}

// ---------------- 4096-point radix-16 Stockham (16^3), 256 threads, one row per block ----------------
template<bool INV, int MODE>
__global__ __launch_bounds__(256) void fft4096(float2* data,
                                               const float2* __restrict__ T1t,
                                               const float2* __restrict__ T2t) {
    __shared__ float2 S[4352];
    const int t = threadIdx.x;
    const int r = blockIdx.x;
    float2* base = data + (size_t)r * 4096;

    float2 x[16], y[16];
    #pragma unroll
    for (int m = 0; m < 16; ++m) x[m] = base[t + 256*m];

    // stage 0: s=1, q=0, ps=t
    dft16<INV>(x, y);
    twiddle16<INV>(y, t, T1t);
    #pragma unroll
    for (int k = 0; k < 16; ++k) S[pidx(16*t + k)] = y[k];
    __syncthreads();
    #pragma unroll
    for (int m = 0; m < 16; ++m) x[m] = S[pidx(t + 256*m)];

    // stage 1: s=16, q=t&15, ps=t-q
    dft16<INV>(x, y);
    {
        const int q = t & 15, ps = t - q;
        twiddle16<INV>(y, ps, T1t);
        __syncthreads();                     // WAR before overwrite
        #pragma unroll
        for (int k = 0; k < 16; ++k) S[pidx(16*ps + q + 16*k)] = y[k];
    }
    __syncthreads();
    #pragma unroll
    for (int m = 0; m < 16; ++m) x[m] = S[pidx(t + 256*m)];

    // stage 2 (final): s=256, ps=0 -> no stage twiddle; output o = t + 256k
    dft16<INV>(x, y);

    if (MODE == M_TW) {
        float2 wb    = wbig(r * t, T1t, T2t);          // per-lane, 2 gathers total
        float2 wstep = wbig(256 * r, T1t, T2t);        // uniform
        #pragma unroll
        for (int k = 0; k < 16; ++k) {
            int o = t + 256*k;
            base[o] = INV ? cmul_conj(y[k], wb) : cmul(y[k], wb);
            wb = INV ? cmul_conj(wb, wstep) : cmul(wb, wstep);
        }
    } else {
        #pragma unroll
        for (int k = 0; k < 16; ++k) {
            int o = t + 256*k;
            float2 v = y[k];
            if (MODE == M_SCALE) {
                const float sc = 1.f / 8388608.f;
                v.x *= sc; v.y *= sc;
            }
            base[o] = v;
        }
    }
}

// ------- fused middle: fwd 2048 FFT + Hilbert mask + inv 2048 FFT + conj four-step twiddle -------
// ONE row per block, 256 threads; r4-final + mask + inv-stage-0 fused in registers.
__global__ __launch_bounds__(256) void fftmid(float2* data,
                                              const float2* __restrict__ T1t,
                                              const float2* __restrict__ T2t) {
    __shared__ float2 S[2176];
    const int t = threadIdx.x;
    const int r = blockIdx.x;
    float2* base = data + (size_t)r * 2048;

    float2 x[8], y[8];
    #pragma unroll
    for (int m = 0; m < 8; ++m) x[m] = base[t + 256*m];

    // ---- forward: radix-8 stages s=1,8,64 ----
    #pragma unroll
    for (int st = 0; st < 3; ++st) {
        const int s = 1 << (3*st);
        const int q = t & (s - 1);
        const int ps = t - q;
        dft8<false>(x, y);
        twiddle8<false, 1>(y, ps, T1t);
        if (st) __syncthreads();
        #pragma unroll
        for (int k = 0; k < 8; ++k) S[pidx(8*ps + q + k*s)] = y[k];
        __syncthreads();
        if (st < 2) {
            #pragma unroll
            for (int m = 0; m < 8; ++m) x[m] = S[pidx(t + 256*m)];
        }
    }
    // ---- fwd final radix-4 (s=512, ps=0) + Hilbert mask + inv stage-0: all in registers ----
    float2 xa[4], xb[4], ya[4], yb[4];
    #pragma unroll
    for (int m = 0; m < 4; ++m) {
        xa[m] = S[pidx(t + 512*m)];
        xb[m] = S[pidx(t + 256 + 512*m)];
    }
    dft4<false>(xa, ya);   // positions o = t + 512k
    dft4<false>(xb, yb);   // positions o = t + 256 + 512k
    {
        float2 z[4];
        float h0 = (t == 0 && r == 0) ? 1.f : 2.f;          // o = t (global k = t*4096+r)
        z[0] = make_float2(ya[0].x * h0, ya[0].y * h0);     // o = t      (<1024)
        z[1] = make_float2(yb[0].x * 2.f, yb[0].y * 2.f);   // o = t+256  (<1024)
        z[2] = make_float2(ya[1].x * 2.f, ya[1].y * 2.f);   // o = t+512  (<1024)
        z[3] = make_float2(yb[1].x * 2.f, yb[1].y * 2.f);   // o = t+768  (<1024)
        dft8_h0_inv(z, y);
        if (t == 0 && r == 0) {                             // corner o=1024 (h=1): ya[2]
            float2 c = ya[2];
            #pragma unroll
            for (int k = 0; k < 8; ++k) {
                if (k & 1) { y[k].x -= c.x; y[k].y -= c.y; }
                else       { y[k].x += c.x; y[k].y += c.y; }
            }
        }
    }
    twiddle8<true, 1>(y, t, T1t);
    __syncthreads();                           // WAR: all r4 reads done before overwrite
    #pragma unroll
    for (int k = 0; k < 8; ++k) S[pidx(8*t + k)] = y[k];
    __syncthreads();
    // ---- inv stages s=8,64 ----
    #pragma unroll
    for (int st = 1; st < 3; ++st) {
        const int s = 1 << (3*st);
        const int q = t & (s - 1);
        const int ps = t - q;
        #pragma unroll
        for (int m = 0; m < 8; ++m) x[m] = S[pidx(t + 256*m)];
        dft8<true>(x, y);
        twiddle8<true, 1>(y, ps, T1t);
        __syncthreads();
        #pragma unroll
        for (int k = 0; k < 8; ++k) S[pidx(8*ps + q + k*s)] = y[k];
        __syncthreads();
    }
    // ---- inverse final radix-4 + conj four-step twiddle + store ----
    #pragma unroll
    for (int m = 0; m < 4; ++m) {
        xa[m] = S[pidx(t + 512*m)];
        xb[m] = S[pidx(t + 256 + 512*m)];
    }
    dft4<true>(xa, ya);
    dft4<true>(xb, yb);
    {
        float2 wka   = wbig(r * t, T1t, T2t);          // per-lane, 2 gathers
        float2 w256  = wbig(256 * r, T1t, T2t);        // uniform
        float2 w512  = cmul(w256, w256);               // uniform
        float2 wkb   = cmul(wka, w256);
        #pragma unroll
        for (int k = 0; k < 4; ++k) {
            int o = t + 512*k;
            base[o]       = cmul_conj(ya[k], wka);
            base[o + 256] = cmul_conj(yb[k], wkb);
            wka = cmul(wka, w512);
            wkb = cmul(wkb, w512);
        }
    }
}

// ---------------- transposes ----------------
// k_pre also generates the twiddle tables in its first 24 (y==0) blocks.
__global__ __launch_bounds__(256) void k_pre(const float* __restrict__ x, float2* __restrict__ A,
                                             float2* T1, float2* T2) {
    __shared__ float tile[32][33];
    int c0 = blockIdx.x * 32;   // n1 tile
    int r0 = blockIdx.y * 32;   // n2 tile
    int tx = threadIdx.x, ty = threadIdx.y;
    if (blockIdx.y == 0 && blockIdx.x < 24) {
        int j = blockIdx.x * 256 + ty * 32 + tx;
        if (j < 4096) {
            double ang = -2.0 * M_PI * (double)j / 4096.0;
            T1[j] = make_float2((float)cos(ang), (float)sin(ang));
        } else if (j < 4096 + 2048) {
            int b = j - 4096;
            double ang = -2.0 * M_PI * (double)b / 8388608.0;
            T2[b] = make_float2((float)cos(ang), (float)sin(ang));
        }
    }
    #pragma unroll
    for (int j = 0; j < 32; j += 8)
        tile[ty + j][tx] = x[(size_t)(r0 + ty + j) * N1 + c0 + tx];
    __syncthreads();
    #pragma unroll
    for (int j = 0; j < 32; j += 8) {
        float v = tile[tx][ty + j];
        A[(size_t)(c0 + ty + j) * N2 + r0 + tx] = make_float2(fmaxf(v, 0.f), fmaxf(-v, 0.f));
    }
}

__global__ __launch_bounds__(256) void k_trans(const float2* __restrict__ in, float2* __restrict__ out,
                                               int inCols, int inRows) {
    __shared__ float2 tile[32][33];
    int c0 = blockIdx.x * 32;
    int r0 = blockIdx.y * 32;
    int tx = threadIdx.x, ty = threadIdx.y;
    #pragma unroll
    for (int j = 0; j < 32; j += 8)
        tile[ty + j][tx] = in[(size_t)(r0 + ty + j) * inCols + c0 + tx];
    __syncthreads();
    #pragma unroll
    for (int j = 0; j < 32; j += 8)
        out[(size_t)(c0 + ty + j) * inRows + r0 + tx] = tile[tx][ty + j];
}

// final transpose + envelope epilogue + deterministic std partials.
__global__ __launch_bounds__(256) void k_post(const float2* __restrict__ A, const float* __restrict__ x,
                                              float* __restrict__ out, float* __restrict__ part) {
    __shared__ float2 tile[32][33];
    __shared__ float red[2][8][32];
    int c0 = blockIdx.x * 32;   // n2 tile
    int r0 = blockIdx.y * 32;   // n1 tile
    int tx = threadIdx.x, ty = threadIdx.y;
    #pragma unroll
    for (int j = 0; j < 32; j += 8)
        tile[ty + j][tx] = A[(size_t)(r0 + ty + j) * N2 + c0 + tx];
    __syncthreads();
    float s1 = 0.f, s2 = 0.f;
    #pragma unroll
    for (int j = 0; j < 32; j += 8) {
        int n2 = c0 + ty + j;
        int n1 = r0 + tx;
        size_t n = (size_t)n2 * N1 + n1;
        float2 w = tile[tx][ty + j];
        float xv = x[n];
        float up = fmaxf(xv, 0.f);
        float dn = fmaxf(-xv, 0.f);
        float hu = w.y - dn;          // H(up)
        float hd = up - w.x;          // H(down)
        float em = sqrtf(up*up + hu*hu);
        float en = sqrtf(dn*dn + hd*hd);
        float avg = 0.5f * (em - en);
        float imf = xv - avg;
        out[NTOT + n] = avg;
        s1 += imf;
        s2 += imf * imf;
    }
    red[0][ty][tx] = s1;
    red[1][ty][tx] = s2;
    __syncthreads();
    if (ty == 0) {
        #pragma unroll
        for (int e = 1; e < 8; ++e) { s1 += red[0][e][tx]; s2 += red[1][e][tx]; }
        int slot = blockIdx.y * 128 + blockIdx.x;   // 64*128 = 8192 slots
        part[slot * 32 + tx]          = s1;
        part[262144 + slot * 32 + tx] = s2;
    }
}

// std over L (ddof=1) from k_post partials. g = b*64 + d, 2048 threads.
__global__ __launch_bounds__(256) void std_final(const float* __restrict__ part, float* __restrict__ scalev) {
    int g = blockIdx.x * 256 + threadIdx.x;
    int b = g >> 6, d = g & 63;
    int dh = d >> 5, dl = d & 31;
    float s1 = 0.f, s2 = 0.f;
    for (int lq = 0; lq < 32; ++lq) {
        int by = lq * 2 + dh;
        #pragma unroll
        for (int ch = 0; ch < 4; ++ch) {
            int slot = by * 128 + b * 4 + ch;
            s1 += part[slot * 32 + dl];
            s2 += part[262144 + slot * 32 + dl];
        }
    }
    float mean = s1 / (float)LL;
    float var  = (s2 - (float)LL * mean * mean) / (float)(LL - 1);
    var = fmaxf(var, 0.f);
    scalev[g] = 1.f / (sqrtf(var) + 0.01f);
}

// imf = (x - avg) * scale
__global__ __launch_bounds__(256) void imf_final(const float* __restrict__ x, float* __restrict__ out,
                                                 const float* __restrict__ scalev) {
    size_t i = ((size_t)blockIdx.x * 256 + threadIdx.x) * 4;
    float4 xv = *(const float4*)(x + i);
    float4 av = *(const float4*)(out + NTOT + i);
    int b = (int)(i >> 18);          // L*D = 2^18
    int d = (int)(i & 63);
    const float* sc = scalev + b * 64;
    float4 v;
    v.x = (xv.x - av.x) * sc[d];
    v.y = (xv.y - av.y) * sc[d + 1];
    v.z = (xv.z - av.z) * sc[d + 2];
    v.w = (xv.w - av.w) * sc[d + 3];
    *(float4*)(out + i) = v;
}

// ---------------- launch ----------------
extern "C" void kernel_launch(void* const* d_in, const int* in_sizes, int n_in,
                              void* d_out, int out_size, void* d_ws, size_t ws_size,
                              hipStream_t stream) {
    const float* x = (const float*)d_in[0];
    float* out = (float*)d_out;
    char* w = (char*)d_ws;

    float2* T1     = (float2*)w;                   // 32 KB
    float2* T2     = (float2*)(w + 32 * 1024);     // 16 KB
    float*  scalev = (float*)(w + 48 * 1024);      // 8 KB
    float2* A      = (float2*)(w + (1 << 20));     // 64 MB scratch
    float2* Bbuf   = (float2*)d_out;               // d_out doubles as 2nd 64 MB buffer
    float*  part   = (float*)d_out;                // 2 MB partials in imf region (free until imf_final)

    hipLaunchKernelGGL(k_pre, dim3(N1/32, N2/32), dim3(32, 8), 0, stream, x, A, T1, T2);
    hipLaunchKernelGGL((fft4096<false, M_TW>), dim3(N1), dim3(256), 0, stream, A, T1, T2);
    hipLaunchKernelGGL(k_trans, dim3(N2/32, N1/32), dim3(32, 8), 0, stream, A, Bbuf, N2, N1);
    hipLaunchKernelGGL(fftmid, dim3(N2), dim3(256), 0, stream, Bbuf, T1, T2);
    hipLaunchKernelGGL(k_trans, dim3(N1/32, N2/32), dim3(32, 8), 0, stream, Bbuf, A, N1, N2);
    hipLaunchKernelGGL((fft4096<true, M_SCALE>), dim3(N1), dim3(256), 0, stream, A, T1, T2);

    hipLaunchKernelGGL(k_post, dim3(N2/32, N1/32), dim3(32, 8), 0, stream, A, x, out, part);
    hipLaunchKernelGGL(std_final, dim3(8), dim3(256), 0, stream, part, scalev);
    hipLaunchKernelGGL(imf_final, dim3(NTOT / 4 / 256), dim3(256), 0, stream, x, out, scalev);
}

// Round 9
// 195.284 us; speedup vs baseline: 1.3781x; 1.0117x over previous
//
#include <hip/hip_runtime.h>
#include <math.h>

#define NTOT 8388608   // 2^23 = 32*4096*64
#define N1   2048
#define N2   4096
#define BB   32
#define LL   4096
#define DD   64

enum { M_NONE = 0, M_TW = 1, M_SCALE = 4 };

__device__ inline float2 cmul(float2 a, float2 b) {
    return make_float2(a.x*b.x - a.y*b.y, a.x*b.y + a.y*b.x);
}
__device__ inline float2 cmul_conj(float2 a, float2 b) {   // a * conj(b)
    return make_float2(a.x*b.x + a.y*b.y, a.y*b.x - a.x*b.y);
}
__device__ inline float2 cadd(float2 a, float2 b){ return make_float2(a.x+b.x, a.y+b.y); }
__device__ inline float2 csub(float2 a, float2 b){ return make_float2(a.x-b.x, a.y-b.y); }
__device__ inline float2 mul_pi(float2 a){ return make_float2(-a.y, a.x); }   // * i
__device__ inline float2 mul_mi(float2 a){ return make_float2(a.y, -a.x); }   // * -i
__device__ inline int pidx(int a){ return a + (a >> 4); }                     // float2 LDS pad

// DFT8: y_k = sum_m x_m W8^{+-km}
template<bool INV>
__device__ inline void dft8(const float2* x, float2* y) {
    const float C = 0.70710678118654752f;
    float2 t0=cadd(x[0],x[4]), t1=cadd(x[1],x[5]), t2=cadd(x[2],x[6]), t3=cadd(x[3],x[7]);
    float2 u0=csub(x[0],x[4]), u1=csub(x[1],x[5]), u2=csub(x[2],x[6]), u3=csub(x[3],x[7]);
    if (!INV) {
        u1 = make_float2(C*(u1.x+u1.y), C*(u1.y-u1.x));
        u2 = mul_mi(u2);
        u3 = make_float2(C*(u3.y-u3.x), -C*(u3.x+u3.y));
    } else {
        u1 = make_float2(C*(u1.x-u1.y), C*(u1.y+u1.x));
        u2 = mul_pi(u2);
        u3 = make_float2(-C*(u3.x+u3.y), C*(u3.x-u3.y));
    }
    {
        float2 s0=cadd(t0,t2), s1=cadd(t1,t3), d0=csub(t0,t2);
        float2 d1 = INV ? mul_pi(csub(t1,t3)) : mul_mi(csub(t1,t3));
        y[0]=cadd(s0,s1); y[4]=csub(s0,s1); y[2]=cadd(d0,d1); y[6]=csub(d0,d1);
    }
    {
        float2 s0=cadd(u0,u2), s1=cadd(u1,u3), d0=csub(u0,u2);
        float2 d1 = INV ? mul_pi(csub(u1,u3)) : mul_mi(csub(u1,u3));
        y[1]=cadd(s0,s1); y[5]=csub(s0,s1); y[3]=cadd(d0,d1); y[7]=csub(d0,d1);
    }
}

// DFT16 = split into even/odd DFT8 + W16^k combine
template<bool INV>
__device__ inline void dft16(const float2* x, float2* y) {
    const float C  = 0.70710678118654752f;
    const float c1 = 0.92387953251128674f;   // cos(pi/8)
    const float s1 = 0.38268343236508977f;   // sin(pi/8)
    float2 e[8], o[8], E[8], O[8];
    #pragma unroll
    for (int m = 0; m < 8; ++m) { e[m] = x[2*m]; o[m] = x[2*m+1]; }
    dft8<INV>(e, E);
    dft8<INV>(o, O);
    O[1] = cmul(O[1], make_float2( c1, INV ?  s1 : -s1));
    O[2] = cmul(O[2], make_float2(  C, INV ?   C : -C ));
    O[3] = cmul(O[3], make_float2( s1, INV ?  c1 : -c1));
    O[4] = INV ? mul_pi(O[4]) : mul_mi(O[4]);
    O[5] = cmul(O[5], make_float2(-s1, INV ?  c1 : -c1));
    O[6] = cmul(O[6], make_float2( -C, INV ?   C : -C ));
    O[7] = cmul(O[7], make_float2(-c1, INV ?  s1 : -s1));
    #pragma unroll
    for (int k = 0; k < 8; ++k) {
        y[k]     = cadd(E[k], O[k]);
        y[k + 8] = csub(E[k], O[k]);
    }
}

// inverse DFT8 with x[4..7] == 0
__device__ inline void dft8_h0_inv(const float2* x, float2* y) {
    const float C = 0.70710678118654752f;
    float2 u1 = make_float2(C*(x[1].x - x[1].y), C*(x[1].y + x[1].x));
    float2 u2 = mul_pi(x[2]);
    float2 u3 = make_float2(-C*(x[3].x + x[3].y), C*(x[3].x - x[3].y));
    {
        float2 s0=cadd(x[0],x[2]), s1=cadd(x[1],x[3]), d0=csub(x[0],x[2]);
        float2 d1 = mul_pi(csub(x[1],x[3]));
        y[0]=cadd(s0,s1); y[4]=csub(s0,s1); y[2]=cadd(d0,d1); y[6]=csub(d0,d1);
    }
    {
        float2 s0=cadd(x[0],u2), s1=cadd(u1,u3), d0=csub(x[0],u2);
        float2 d1 = mul_pi(csub(u1,u3));
        y[1]=cadd(s0,s1); y[5]=csub(s0,s1); y[3]=cadd(d0,d1); y[7]=csub(d0,d1);
    }
}

// inverse DFT16 with x[8..15] == 0 (only x[0..7] passed)
__device__ inline void dft16_h0_inv(const float2* x, float2* y) {
    const float C  = 0.70710678118654752f;
    const float c1 = 0.92387953251128674f;
    const float s1 = 0.38268343236508977f;
    float2 e4[4] = { x[0], x[2], x[4], x[6] };
    float2 o4[4] = { x[1], x[3], x[5], x[7] };
    float2 E[8], O[8];
    dft8_h0_inv(e4, E);
    dft8_h0_inv(o4, O);
    O[1] = cmul(O[1], make_float2( c1,  s1));
    O[2] = cmul(O[2], make_float2(  C,   C));
    O[3] = cmul(O[3], make_float2( s1,  c1));
    O[4] = mul_pi(O[4]);
    O[5] = cmul(O[5], make_float2(-s1,  c1));
    O[6] = cmul(O[6], make_float2( -C,   C));
    O[7] = cmul(O[7], make_float2(-c1,  s1));
    #pragma unroll
    for (int k = 0; k < 8; ++k) {
        y[k]     = cadd(E[k], O[k]);
        y[k + 8] = csub(E[k], O[k]);
    }
}

template<bool INV>
__device__ inline void dft4(const float2* u, float2* y) {
    float2 s0=cadd(u[0],u[2]), s1=cadd(u[1],u[3]), d0=csub(u[0],u[2]);
    float2 d1 = INV ? mul_pi(csub(u[1],u[3])) : mul_mi(csub(u[1],u[3]));
    y[0]=cadd(s0,s1); y[2]=csub(s0,s1); y[1]=cadd(d0,d1); y[3]=csub(d0,d1);
}

// y_k *= W^{+-ps*k}, k=1..7: ONE gather + cmul power tree
template<bool INV, int SH>
__device__ inline void twiddle8(float2* y, int ps, const float2* __restrict__ T1t) {
    float2 w1 = T1t[(ps << SH) & 4095];
    float2 w2 = cmul(w1, w1);
    float2 w3 = cmul(w2, w1);
    float2 w4 = cmul(w2, w2);
    float2 w5 = cmul(w4, w1);
    float2 w6 = cmul(w3, w3);
    float2 w7 = cmul(w4, w3);
    if (!INV) {
        y[1]=cmul(y[1],w1); y[2]=cmul(y[2],w2); y[3]=cmul(y[3],w3);
        y[4]=cmul(y[4],w4); y[5]=cmul(y[5],w5); y[6]=cmul(y[6],w6); y[7]=cmul(y[7],w7);
    } else {
        y[1]=cmul_conj(y[1],w1); y[2]=cmul_conj(y[2],w2); y[3]=cmul_conj(y[3],w3);
        y[4]=cmul_conj(y[4],w4); y[5]=cmul_conj(y[5],w5); y[6]=cmul_conj(y[6],w6); y[7]=cmul_conj(y[7],w7);
    }
}

// y_k *= W^{+-ps*k}, k=1..15 (SH=0: N=4096, SH=1: N=2048)
template<bool INV, int SH>
__device__ inline void twiddle16(float2* y, int ps, const float2* __restrict__ T1t) {
    float2 w[16];
    w[1] = T1t[(ps << SH) & 4095];
    w[2] = cmul(w[1], w[1]);
    w[3] = cmul(w[2], w[1]);
    w[4] = cmul(w[2], w[2]);
    w[5] = cmul(w[4], w[1]);
    w[6] = cmul(w[3], w[3]);
    w[7] = cmul(w[4], w[3]);
    w[8] = cmul(w[4], w[4]);
    w[9] = cmul(w[8], w[1]);
    w[10]= cmul(w[5], w[5]);
    w[11]= cmul(w[8], w[3]);
    w[12]= cmul(w[6], w[6]);
    w[13]= cmul(w[8], w[5]);
    w[14]= cmul(w[7], w[7]);
    w[15]= cmul(w[8], w[7]);
    #pragma unroll
    for (int k = 1; k < 16; ++k)
        y[k] = INV ? cmul_conj(y[k], w[k]) : cmul(y[k], w[k]);
}

// W_2^23^{t} from split tables (t < 2^23)
__device__ inline float2 wbig(int t, const float2* __restrict__ T1t, const float2* __restrict__ T2t) {
    return cmul(T1t[t >> 11], T2t[t & 2047]);
}

// ---------------- 4096-point radix-16 Stockham (16^3), 256 threads, one row per block ----------------
template<bool INV, int MODE>
__global__ __launch_bounds__(256) void fft4096(float2* data,
                                               const float2* __restrict__ T1t,
                                               const float2* __restrict__ T2t) {
    __shared__ float2 S[4352];
    const int t = threadIdx.x;
    const int r = blockIdx.x;
    float2* base = data + (size_t)r * 4096;

    float2 x[16], y[16];
    #pragma unroll
    for (int m = 0; m < 16; ++m) x[m] = base[t + 256*m];

    dft16<INV>(x, y);
    twiddle16<INV, 0>(y, t, T1t);
    #pragma unroll
    for (int k = 0; k < 16; ++k) S[pidx(16*t + k)] = y[k];
    __syncthreads();
    #pragma unroll
    for (int m = 0; m < 16; ++m) x[m] = S[pidx(t + 256*m)];

    dft16<INV>(x, y);
    {
        const int q = t & 15, ps = t - q;
        twiddle16<INV, 0>(y, ps, T1t);
        __syncthreads();
        #pragma unroll
        for (int k = 0; k < 16; ++k) S[pidx(16*ps + q + 16*k)] = y[k];
    }
    __syncthreads();
    #pragma unroll
    for (int m = 0; m < 16; ++m) x[m] = S[pidx(t + 256*m)];

    dft16<INV>(x, y);

    if (MODE == M_TW) {
        float2 wb    = wbig(r * t, T1t, T2t);
        float2 wstep = wbig(256 * r, T1t, T2t);
        #pragma unroll
        for (int k = 0; k < 16; ++k) {
            int o = t + 256*k;
            base[o] = INV ? cmul_conj(y[k], wb) : cmul(y[k], wb);
            wb = INV ? cmul_conj(wb, wstep) : cmul(wb, wstep);
        }
    } else {
        #pragma unroll
        for (int k = 0; k < 16; ++k) {
            int o = t + 256*k;
            float2 v = y[k];
            if (MODE == M_SCALE) {
                const float sc = 1.f / 8388608.f;
                v.x *= sc; v.y *= sc;
            }
            base[o] = v;
        }
    }
}

// ------- fused middle: fwd 2048 FFT + Hilbert mask + inv 2048 FFT + conj four-step twiddle -------
// Radix-16 (2048 = 16*16*8), 128 threads, one row per block.
// Fwd-final radix-8 pair (j=t, t+128) + mask + inv radix-16 stage-0 fused in registers.
__global__ __launch_bounds__(128) void fftmid(float2* data,
                                              const float2* __restrict__ T1t,
                                              const float2* __restrict__ T2t) {
    __shared__ float2 S[2176];
    const int t = threadIdx.x;         // 0..127
    const int r = blockIdx.x;          // 0..4095
    float2* base = data + (size_t)r * 2048;

    float2 x[16], y[16];
    #pragma unroll
    for (int m = 0; m < 16; ++m) x[m] = base[t + 128*m];

    // ---- fwd stage 0: radix-16, s=1, ps=t ----
    dft16<false>(x, y);
    twiddle16<false, 1>(y, t, T1t);
    #pragma unroll
    for (int k = 0; k < 16; ++k) S[pidx(16*t + k)] = y[k];
    __syncthreads();
    #pragma unroll
    for (int m = 0; m < 16; ++m) x[m] = S[pidx(t + 128*m)];

    // ---- fwd stage 1: radix-16, s=16 ----
    dft16<false>(x, y);
    {
        const int q = t & 15, ps = t - q;
        twiddle16<false, 1>(y, ps, T1t);
        __syncthreads();
        #pragma unroll
        for (int k = 0; k < 16; ++k) S[pidx(16*ps + q + 16*k)] = y[k];
    }
    __syncthreads();

    // ---- fwd final radix-8 (s=256, ps=0), two butterflies j=t and j=t+128 ----
    float2 xa[8], xb[8], ya[8], yb[8];
    #pragma unroll
    for (int m = 0; m < 8; ++m) {
        xa[m] = S[pidx(t + 256*m)];
        xb[m] = S[pidx(t + 128 + 256*m)];
    }
    dft8<false>(xa, ya);   // positions o = t + 256k
    dft8<false>(xb, yb);   // positions o = t + 128 + 256k
    // ---- Hilbert mask (o<1024 survives, o=1024 corner) + inv radix-16 stage 0, in registers ----
    // inverse butterfly j=t inputs: {t + 128m} = interleave of ya (even m) and yb (odd m)
    {
        float2 z[8];
        float h0 = (t == 0 && r == 0) ? 1.f : 2.f;   // o = t, global k = t*4096+r
        z[0] = make_float2(ya[0].x * h0,  ya[0].y * h0);
        z[1] = make_float2(yb[0].x * 2.f, yb[0].y * 2.f);
        z[2] = make_float2(ya[1].x * 2.f, ya[1].y * 2.f);
        z[3] = make_float2(yb[1].x * 2.f, yb[1].y * 2.f);
        z[4] = make_float2(ya[2].x * 2.f, ya[2].y * 2.f);
        z[5] = make_float2(yb[2].x * 2.f, yb[2].y * 2.f);
        z[6] = make_float2(ya[3].x * 2.f, ya[3].y * 2.f);
        z[7] = make_float2(yb[3].x * 2.f, yb[3].y * 2.f);
        dft16_h0_inv(z, y);
        if (t == 0 && r == 0) {                      // corner o=1024 = ya[4] (h=1, r==0 only)
            float2 c = ya[4];                        // delta at position 8 of 16: (-1)^idx
            #pragma unroll
            for (int k = 0; k < 16; ++k) {
                if (k & 1) { y[k].x -= c.x; y[k].y -= c.y; }
                else       { y[k].x += c.x; y[k].y += c.y; }
            }
        }
    }
    twiddle16<true, 1>(y, t, T1t);
    __syncthreads();                                 // WAR: all final gathers done
    #pragma unroll
    for (int k = 0; k < 16; ++k) S[pidx(16*t + k)] = y[k];
    __syncthreads();

    // ---- inv stage 1: radix-16, s=16 ----
    #pragma unroll
    for (int m = 0; m < 16; ++m) x[m] = S[pidx(t + 128*m)];
    dft16<true>(x, y);
    {
        const int q = t & 15, ps = t - q;
        twiddle16<true, 1>(y, ps, T1t);
        __syncthreads();
        #pragma unroll
        for (int k = 0; k < 16; ++k) S[pidx(16*ps + q + 16*k)] = y[k];
    }
    __syncthreads();

    // ---- inv final radix-8 (s=256, ps=0) + conj four-step twiddle + store ----
    #pragma unroll
    for (int m = 0; m < 8; ++m) {
        xa[m] = S[pidx(t + 256*m)];
        xb[m] = S[pidx(t + 128 + 256*m)];
    }
    dft8<true>(xa, ya);
    dft8<true>(xb, yb);
    {
        float2 wka  = wbig(r * t, T1t, T2t);         // per-lane, 2 gathers
        float2 w128 = wbig(128 * r, T1t, T2t);       // uniform
        float2 w256 = cmul(w128, w128);              // uniform
        float2 wkb  = cmul(wka, w128);
        #pragma unroll
        for (int k = 0; k < 8; ++k) {
            int o = t + 256*k;
            base[o]       = cmul_conj(ya[k], wka);
            base[o + 128] = cmul_conj(yb[k], wkb);
            wka = cmul(wka, w256);
            wkb = cmul(wkb, w256);
        }
    }
}

// ---------------- transposes ----------------
// k_pre also generates the twiddle tables in its first 24 (y==0) blocks.
__global__ __launch_bounds__(256) void k_pre(const float* __restrict__ x, float2* __restrict__ A,
                                             float2* T1, float2* T2) {
    __shared__ float tile[32][33];
    int c0 = blockIdx.x * 32;   // n1 tile
    int r0 = blockIdx.y * 32;   // n2 tile
    int tx = threadIdx.x, ty = threadIdx.y;
    if (blockIdx.y == 0 && blockIdx.x < 24) {
        int j = blockIdx.x * 256 + ty * 32 + tx;
        if (j < 4096) {
            double ang = -2.0 * M_PI * (double)j / 4096.0;
            T1[j] = make_float2((float)cos(ang), (float)sin(ang));
        } else if (j < 4096 + 2048) {
            int b = j - 4096;
            double ang = -2.0 * M_PI * (double)b / 8388608.0;
            T2[b] = make_float2((float)cos(ang), (float)sin(ang));
        }
    }
    #pragma unroll
    for (int j = 0; j < 32; j += 8)
        tile[ty + j][tx] = x[(size_t)(r0 + ty + j) * N1 + c0 + tx];
    __syncthreads();
    #pragma unroll
    for (int j = 0; j < 32; j += 8) {
        float v = tile[tx][ty + j];
        A[(size_t)(c0 + ty + j) * N2 + r0 + tx] = make_float2(fmaxf(v, 0.f), fmaxf(-v, 0.f));
    }
}

__global__ __launch_bounds__(256) void k_trans(const float2* __restrict__ in, float2* __restrict__ out,
                                               int inCols, int inRows) {
    __shared__ float2 tile[32][33];
    int c0 = blockIdx.x * 32;
    int r0 = blockIdx.y * 32;
    int tx = threadIdx.x, ty = threadIdx.y;
    #pragma unroll
    for (int j = 0; j < 32; j += 8)
        tile[ty + j][tx] = in[(size_t)(r0 + ty + j) * inCols + c0 + tx];
    __syncthreads();
    #pragma unroll
    for (int j = 0; j < 32; j += 8)
        out[(size_t)(c0 + ty + j) * inRows + r0 + tx] = tile[tx][ty + j];
}

// final transpose + envelope epilogue + deterministic std partials.
__global__ __launch_bounds__(256) void k_post(const float2* __restrict__ A, const float* __restrict__ x,
                                              float* __restrict__ out, float* __restrict__ part) {
    __shared__ float2 tile[32][33];
    __shared__ float red[2][8][32];
    int c0 = blockIdx.x * 32;   // n2 tile
    int r0 = blockIdx.y * 32;   // n1 tile
    int tx = threadIdx.x, ty = threadIdx.y;
    #pragma unroll
    for (int j = 0; j < 32; j += 8)
        tile[ty + j][tx] = A[(size_t)(r0 + ty + j) * N2 + c0 + tx];
    __syncthreads();
    float s1 = 0.f, s2 = 0.f;
    #pragma unroll
    for (int j = 0; j < 32; j += 8) {
        int n2 = c0 + ty + j;
        int n1 = r0 + tx;
        size_t n = (size_t)n2 * N1 + n1;
        float2 w = tile[tx][ty + j];
        float xv = x[n];
        float up = fmaxf(xv, 0.f);
        float dn = fmaxf(-xv, 0.f);
        float hu = w.y - dn;          // H(up)
        float hd = up - w.x;          // H(down)
        float em = sqrtf(up*up + hu*hu);
        float en = sqrtf(dn*dn + hd*hd);
        float avg = 0.5f * (em - en);
        float imf = xv - avg;
        out[NTOT + n] = avg;
        s1 += imf;
        s2 += imf * imf;
    }
    red[0][ty][tx] = s1;
    red[1][ty][tx] = s2;
    __syncthreads();
    if (ty == 0) {
        #pragma unroll
        for (int e = 1; e < 8; ++e) { s1 += red[0][e][tx]; s2 += red[1][e][tx]; }
        int slot = blockIdx.y * 128 + blockIdx.x;   // 64*128 = 8192 slots
        part[slot * 32 + tx]          = s1;
        part[262144 + slot * 32 + tx] = s2;
    }
}

// std over L (ddof=1) from k_post partials. g = b*64 + d, 2048 threads.
__global__ __launch_bounds__(256) void std_final(const float* __restrict__ part, float* __restrict__ scalev) {
    int g = blockIdx.x * 256 + threadIdx.x;
    int b = g >> 6, d = g & 63;
    int dh = d >> 5, dl = d & 31;
    float s1 = 0.f, s2 = 0.f;
    for (int lq = 0; lq < 32; ++lq) {
        int by = lq * 2 + dh;
        #pragma unroll
        for (int ch = 0; ch < 4; ++ch) {
            int slot = by * 128 + b * 4 + ch;
            s1 += part[slot * 32 + dl];
            s2 += part[262144 + slot * 32 + dl];
        }
    }
    float mean = s1 / (float)LL;
    float var  = (s2 - (float)LL * mean * mean) / (float)(LL - 1);
    var = fmaxf(var, 0.f);
    scalev[g] = 1.f / (sqrtf(var) + 0.01f);
}

// imf = (x - avg) * scale
__global__ __launch_bounds__(256) void imf_final(const float* __restrict__ x, float* __restrict__ out,
                                                 const float* __restrict__ scalev) {
    size_t i = ((size_t)blockIdx.x * 256 + threadIdx.x) * 4;
    float4 xv = *(const float4*)(x + i);
    float4 av = *(const float4*)(out + NTOT + i);
    int b = (int)(i >> 18);          // L*D = 2^18
    int d = (int)(i & 63);
    const float* sc = scalev + b * 64;
    float4 v;
    v.x = (xv.x - av.x) * sc[d];
    v.y = (xv.y - av.y) * sc[d + 1];
    v.z = (xv.z - av.z) * sc[d + 2];
    v.w = (xv.w - av.w) * sc[d + 3];
    *(float4*)(out + i) = v;
}

// ---------------- launch ----------------
extern "C" void kernel_launch(void* const* d_in, const int* in_sizes, int n_in,
                              void* d_out, int out_size, void* d_ws, size_t ws_size,
                              hipStream_t stream) {
    const float* x = (const float*)d_in[0];
    float* out = (float*)d_out;
    char* w = (char*)d_ws;

    float2* T1     = (float2*)w;                   // 32 KB
    float2* T2     = (float2*)(w + 32 * 1024);     // 16 KB
    float*  scalev = (float*)(w + 48 * 1024);      // 8 KB
    float2* A      = (float2*)(w + (1 << 20));     // 64 MB scratch
    float2* Bbuf   = (float2*)d_out;               // d_out doubles as 2nd 64 MB buffer
    float*  part   = (float*)d_out;                // 2 MB partials in imf region (free until imf_final)

    hipLaunchKernelGGL(k_pre, dim3(N1/32, N2/32), dim3(32, 8), 0, stream, x, A, T1, T2);
    hipLaunchKernelGGL((fft4096<false, M_TW>), dim3(N1), dim3(256), 0, stream, A, T1, T2);
    hipLaunchKernelGGL(k_trans, dim3(N2/32, N1/32), dim3(32, 8), 0, stream, A, Bbuf, N2, N1);
    hipLaunchKernelGGL(fftmid, dim3(N2), dim3(128), 0, stream, Bbuf, T1, T2);
    hipLaunchKernelGGL(k_trans, dim3(N1/32, N2/32), dim3(32, 8), 0, stream, Bbuf, A, N1, N2);
    hipLaunchKernelGGL((fft4096<true, M_SCALE>), dim3(N1), dim3(256), 0, stream, A, T1, T2);

    hipLaunchKernelGGL(k_post, dim3(N2/32, N1/32), dim3(32, 8), 0, stream, A, x, out, part);
    hipLaunchKernelGGL(std_final, dim3(8), dim3(256), 0, stream, part, scalev);
    hipLaunchKernelGGL(imf_final, dim3(NTOT / 4 / 256), dim3(256), 0, stream, x, out, scalev);
}

// Round 10
// 189.096 us; speedup vs baseline: 1.4232x; 1.0327x over previous
//
#include <hip/hip_runtime.h>
#include <math.h>

#define NTOT 8388608   // 2^23 = 32*4096*64
#define N1   2048
#define N2   4096
#define BB   32
#define LL   4096
#define DD   64

enum { M_NONE = 0, M_TW = 1, M_SCALE = 4 };

__device__ inline float2 cmul(float2 a, float2 b) {
    return make_float2(a.x*b.x - a.y*b.y, a.x*b.y + a.y*b.x);
}
__device__ inline float2 cmul_conj(float2 a, float2 b) {   // a * conj(b)
    return make_float2(a.x*b.x + a.y*b.y, a.y*b.x - a.x*b.y);
}
__device__ inline float2 cadd(float2 a, float2 b){ return make_float2(a.x+b.x, a.y+b.y); }
__device__ inline float2 csub(float2 a, float2 b){ return make_float2(a.x-b.x, a.y-b.y); }
__device__ inline float2 mul_pi(float2 a){ return make_float2(-a.y, a.x); }   // * i
__device__ inline float2 mul_mi(float2 a){ return make_float2(a.y, -a.x); }   // * -i
__device__ inline int pidx(int a){ return a + (a >> 4); }                     // float2 LDS pad

// DFT8: y_k = sum_m x_m W8^{+-km}
template<bool INV>
__device__ inline void dft8(const float2* x, float2* y) {
    const float C = 0.70710678118654752f;
    float2 t0=cadd(x[0],x[4]), t1=cadd(x[1],x[5]), t2=cadd(x[2],x[6]), t3=cadd(x[3],x[7]);
    float2 u0=csub(x[0],x[4]), u1=csub(x[1],x[5]), u2=csub(x[2],x[6]), u3=csub(x[3],x[7]);
    if (!INV) {
        u1 = make_float2(C*(u1.x+u1.y), C*(u1.y-u1.x));
        u2 = mul_mi(u2);
        u3 = make_float2(C*(u3.y-u3.x), -C*(u3.x+u3.y));
    } else {
        u1 = make_float2(C*(u1.x-u1.y), C*(u1.y+u1.x));
        u2 = mul_pi(u2);
        u3 = make_float2(-C*(u3.x+u3.y), C*(u3.x-u3.y));
    }
    {
        float2 s0=cadd(t0,t2), s1=cadd(t1,t3), d0=csub(t0,t2);
        float2 d1 = INV ? mul_pi(csub(t1,t3)) : mul_mi(csub(t1,t3));
        y[0]=cadd(s0,s1); y[4]=csub(s0,s1); y[2]=cadd(d0,d1); y[6]=csub(d0,d1);
    }
    {
        float2 s0=cadd(u0,u2), s1=cadd(u1,u3), d0=csub(u0,u2);
        float2 d1 = INV ? mul_pi(csub(u1,u3)) : mul_mi(csub(u1,u3));
        y[1]=cadd(s0,s1); y[5]=csub(s0,s1); y[3]=cadd(d0,d1); y[7]=csub(d0,d1);
    }
}

// DFT16 = split into even/odd DFT8 + W16^k combine
template<bool INV>
__device__ inline void dft16(const float2* x, float2* y) {
    const float C  = 0.70710678118654752f;
    const float c1 = 0.92387953251128674f;   // cos(pi/8)
    const float s1 = 0.38268343236508977f;   // sin(pi/8)
    float2 e[8], o[8], E[8], O[8];
    #pragma unroll
    for (int m = 0; m < 8; ++m) { e[m] = x[2*m]; o[m] = x[2*m+1]; }
    dft8<INV>(e, E);
    dft8<INV>(o, O);
    O[1] = cmul(O[1], make_float2( c1, INV ?  s1 : -s1));
    O[2] = cmul(O[2], make_float2(  C, INV ?   C : -C ));
    O[3] = cmul(O[3], make_float2( s1, INV ?  c1 : -c1));
    O[4] = INV ? mul_pi(O[4]) : mul_mi(O[4]);
    O[5] = cmul(O[5], make_float2(-s1, INV ?  c1 : -c1));
    O[6] = cmul(O[6], make_float2( -C, INV ?   C : -C ));
    O[7] = cmul(O[7], make_float2(-c1, INV ?  s1 : -s1));
    #pragma unroll
    for (int k = 0; k < 8; ++k) {
        y[k]     = cadd(E[k], O[k]);
        y[k + 8] = csub(E[k], O[k]);
    }
}

// inverse DFT8 with x[4..7] == 0
__device__ inline void dft8_h0_inv(const float2* x, float2* y) {
    const float C = 0.70710678118654752f;
    float2 u1 = make_float2(C*(x[1].x - x[1].y), C*(x[1].y + x[1].x));
    float2 u2 = mul_pi(x[2]);
    float2 u3 = make_float2(-C*(x[3].x + x[3].y), C*(x[3].x - x[3].y));
    {
        float2 s0=cadd(x[0],x[2]), s1=cadd(x[1],x[3]), d0=csub(x[0],x[2]);
        float2 d1 = mul_pi(csub(x[1],x[3]));
        y[0]=cadd(s0,s1); y[4]=csub(s0,s1); y[2]=cadd(d0,d1); y[6]=csub(d0,d1);
    }
    {
        float2 s0=cadd(x[0],u2), s1=cadd(u1,u3), d0=csub(x[0],u2);
        float2 d1 = mul_pi(csub(u1,u3));
        y[1]=cadd(s0,s1); y[5]=csub(s0,s1); y[3]=cadd(d0,d1); y[7]=csub(d0,d1);
    }
}

// inverse DFT16 with x[8..15] == 0 (only x[0..7] passed)
__device__ inline void dft16_h0_inv(const float2* x, float2* y) {
    const float C  = 0.70710678118654752f;
    const float c1 = 0.92387953251128674f;
    const float s1 = 0.38268343236508977f;
    float2 e4[4] = { x[0], x[2], x[4], x[6] };
    float2 o4[4] = { x[1], x[3], x[5], x[7] };
    float2 E[8], O[8];
    dft8_h0_inv(e4, E);
    dft8_h0_inv(o4, O);
    O[1] = cmul(O[1], make_float2( c1,  s1));
    O[2] = cmul(O[2], make_float2(  C,   C));
    O[3] = cmul(O[3], make_float2( s1,  c1));
    O[4] = mul_pi(O[4]);
    O[5] = cmul(O[5], make_float2(-s1,  c1));
    O[6] = cmul(O[6], make_float2( -C,   C));
    O[7] = cmul(O[7], make_float2(-c1,  s1));
    #pragma unroll
    for (int k = 0; k < 8; ++k) {
        y[k]     = cadd(E[k], O[k]);
        y[k + 8] = csub(E[k], O[k]);
    }
}

template<bool INV>
__device__ inline void dft4(const float2* u, float2* y) {
    float2 s0=cadd(u[0],u[2]), s1=cadd(u[1],u[3]), d0=csub(u[0],u[2]);
    float2 d1 = INV ? mul_pi(csub(u[1],u[3])) : mul_mi(csub(u[1],u[3]));
    y[0]=cadd(s0,s1); y[2]=csub(s0,s1); y[1]=cadd(d0,d1); y[3]=csub(d0,d1);
}

// y_k *= W^{+-ps*k}, k=1..7: ONE gather + cmul power tree
template<bool INV, int SH>
__device__ inline void twiddle8(float2* y, int ps, const float2* __restrict__ T1t) {
    float2 w1 = T1t[(ps << SH) & 4095];
    float2 w2 = cmul(w1, w1);
    float2 w3 = cmul(w2, w1);
    float2 w4 = cmul(w2, w2);
    float2 w5 = cmul(w4, w1);
    float2 w6 = cmul(w3, w3);
    float2 w7 = cmul(w4, w3);
    if (!INV) {
        y[1]=cmul(y[1],w1); y[2]=cmul(y[2],w2); y[3]=cmul(y[3],w3);
        y[4]=cmul(y[4],w4); y[5]=cmul(y[5],w5); y[6]=cmul(y[6],w6); y[7]=cmul(y[7],w7);
    } else {
        y[1]=cmul_conj(y[1],w1); y[2]=cmul_conj(y[2],w2); y[3]=cmul_conj(y[3],w3);
        y[4]=cmul_conj(y[4],w4); y[5]=cmul_conj(y[5],w5); y[6]=cmul_conj(y[6],w6); y[7]=cmul_conj(y[7],w7);
    }
}

// y_k *= W^{+-ps*k}, k=1..15 (SH=0: N=4096, SH=1: N=2048)
template<bool INV, int SH>
__device__ inline void twiddle16(float2* y, int ps, const float2* __restrict__ T1t) {
    float2 w[16];
    w[1] = T1t[(ps << SH) & 4095];
    w[2] = cmul(w[1], w[1]);
    w[3] = cmul(w[2], w[1]);
    w[4] = cmul(w[2], w[2]);
    w[5] = cmul(w[4], w[1]);
    w[6] = cmul(w[3], w[3]);
    w[7] = cmul(w[4], w[3]);
    w[8] = cmul(w[4], w[4]);
    w[9] = cmul(w[8], w[1]);
    w[10]= cmul(w[5], w[5]);
    w[11]= cmul(w[8], w[3]);
    w[12]= cmul(w[6], w[6]);
    w[13]= cmul(w[8], w[5]);
    w[14]= cmul(w[7], w[7]);
    w[15]= cmul(w[8], w[7]);
    #pragma unroll
    for (int k = 1; k < 16; ++k)
        y[k] = INV ? cmul_conj(y[k], w[k]) : cmul(y[k], w[k]);
}

// W_2^23^{t} from split tables (t < 2^23)
__device__ inline float2 wbig(int t, const float2* __restrict__ T1t, const float2* __restrict__ T2t) {
    return cmul(T1t[t >> 11], T2t[t & 2047]);
}

// ---------------- 4096-point radix-16 Stockham (16^3), 256 threads, one row per block ----------------
template<bool INV, int MODE>
__global__ __launch_bounds__(256) void fft4096(float2* data,
                                               const float2* __restrict__ T1t,
                                               const float2* __restrict__ T2t) {
    __shared__ float2 S[4352];
    const int t = threadIdx.x;
    const int r = blockIdx.x;
    float2* base = data + (size_t)r * 4096;

    float2 x[16], y[16];
    #pragma unroll
    for (int m = 0; m < 16; ++m) x[m] = base[t + 256*m];

    dft16<INV>(x, y);
    twiddle16<INV, 0>(y, t, T1t);
    #pragma unroll
    for (int k = 0; k < 16; ++k) S[pidx(16*t + k)] = y[k];
    __syncthreads();
    #pragma unroll
    for (int m = 0; m < 16; ++m) x[m] = S[pidx(t + 256*m)];

    dft16<INV>(x, y);
    {
        const int q = t & 15, ps = t - q;
        twiddle16<INV, 0>(y, ps, T1t);
        __syncthreads();
        #pragma unroll
        for (int k = 0; k < 16; ++k) S[pidx(16*ps + q + 16*k)] = y[k];
    }
    __syncthreads();
    #pragma unroll
    for (int m = 0; m < 16; ++m) x[m] = S[pidx(t + 256*m)];

    dft16<INV>(x, y);

    if (MODE == M_TW) {
        float2 wb    = wbig(r * t, T1t, T2t);
        float2 wstep = wbig(256 * r, T1t, T2t);
        #pragma unroll
        for (int k = 0; k < 16; ++k) {
            int o = t + 256*k;
            base[o] = INV ? cmul_conj(y[k], wb) : cmul(y[k], wb);
            wb = INV ? cmul_conj(wb, wstep) : cmul(wb, wstep);
        }
    } else {
        #pragma unroll
        for (int k = 0; k < 16; ++k) {
            int o = t + 256*k;
            float2 v = y[k];
            if (MODE == M_SCALE) {
                const float sc = 1.f / 8388608.f;
                v.x *= sc; v.y *= sc;
            }
            base[o] = v;
        }
    }
}

// ------- fused middle: fwd 2048 FFT + Hilbert mask + inv 2048 FFT + conj four-step twiddle -------
// Radix-16 (2048 = 16*16*8), 128 threads, one row per block.
__global__ __launch_bounds__(128) void fftmid(float2* data,
                                              const float2* __restrict__ T1t,
                                              const float2* __restrict__ T2t) {
    __shared__ float2 S[2176];
    const int t = threadIdx.x;         // 0..127
    const int r = blockIdx.x;          // 0..4095
    float2* base = data + (size_t)r * 2048;

    float2 x[16], y[16];
    #pragma unroll
    for (int m = 0; m < 16; ++m) x[m] = base[t + 128*m];

    // ---- fwd stage 0: radix-16, s=1, ps=t ----
    dft16<false>(x, y);
    twiddle16<false, 1>(y, t, T1t);
    #pragma unroll
    for (int k = 0; k < 16; ++k) S[pidx(16*t + k)] = y[k];
    __syncthreads();
    #pragma unroll
    for (int m = 0; m < 16; ++m) x[m] = S[pidx(t + 128*m)];

    // ---- fwd stage 1: radix-16, s=16 ----
    dft16<false>(x, y);
    {
        const int q = t & 15, ps = t - q;
        twiddle16<false, 1>(y, ps, T1t);
        __syncthreads();
        #pragma unroll
        for (int k = 0; k < 16; ++k) S[pidx(16*ps + q + 16*k)] = y[k];
    }
    __syncthreads();

    // ---- fwd final radix-8 (s=256, ps=0), two butterflies j=t and j=t+128 ----
    float2 xa[8], xb[8], ya[8], yb[8];
    #pragma unroll
    for (int m = 0; m < 8; ++m) {
        xa[m] = S[pidx(t + 256*m)];
        xb[m] = S[pidx(t + 128 + 256*m)];
    }
    dft8<false>(xa, ya);   // positions o = t + 256k
    dft8<false>(xb, yb);   // positions o = t + 128 + 256k
    // ---- Hilbert mask + inv radix-16 stage 0, in registers ----
    {
        float2 z[8];
        float h0 = (t == 0 && r == 0) ? 1.f : 2.f;   // o = t, global k = t*4096+r
        z[0] = make_float2(ya[0].x * h0,  ya[0].y * h0);
        z[1] = make_float2(yb[0].x * 2.f, yb[0].y * 2.f);
        z[2] = make_float2(ya[1].x * 2.f, ya[1].y * 2.f);
        z[3] = make_float2(yb[1].x * 2.f, yb[1].y * 2.f);
        z[4] = make_float2(ya[2].x * 2.f, ya[2].y * 2.f);
        z[5] = make_float2(yb[2].x * 2.f, yb[2].y * 2.f);
        z[6] = make_float2(ya[3].x * 2.f, ya[3].y * 2.f);
        z[7] = make_float2(yb[3].x * 2.f, yb[3].y * 2.f);
        dft16_h0_inv(z, y);
        if (t == 0 && r == 0) {                      // corner o=1024 = ya[4]
            float2 c = ya[4];
            #pragma unroll
            for (int k = 0; k < 16; ++k) {
                if (k & 1) { y[k].x -= c.x; y[k].y -= c.y; }
                else       { y[k].x += c.x; y[k].y += c.y; }
            }
        }
    }
    twiddle16<true, 1>(y, t, T1t);
    __syncthreads();
    #pragma unroll
    for (int k = 0; k < 16; ++k) S[pidx(16*t + k)] = y[k];
    __syncthreads();

    // ---- inv stage 1: radix-16, s=16 ----
    #pragma unroll
    for (int m = 0; m < 16; ++m) x[m] = S[pidx(t + 128*m)];
    dft16<true>(x, y);
    {
        const int q = t & 15, ps = t - q;
        twiddle16<true, 1>(y, ps, T1t);
        __syncthreads();
        #pragma unroll
        for (int k = 0; k < 16; ++k) S[pidx(16*ps + q + 16*k)] = y[k];
    }
    __syncthreads();

    // ---- inv final radix-8 (s=256, ps=0) + conj four-step twiddle + store ----
    #pragma unroll
    for (int m = 0; m < 8; ++m) {
        xa[m] = S[pidx(t + 256*m)];
        xb[m] = S[pidx(t + 128 + 256*m)];
    }
    dft8<true>(xa, ya);
    dft8<true>(xb, yb);
    {
        float2 wka  = wbig(r * t, T1t, T2t);         // per-lane, 2 gathers
        float2 w128 = wbig(128 * r, T1t, T2t);       // uniform
        float2 w256 = cmul(w128, w128);              // uniform
        float2 wkb  = cmul(wka, w128);
        #pragma unroll
        for (int k = 0; k < 8; ++k) {
            int o = t + 256*k;
            base[o]       = cmul_conj(ya[k], wka);
            base[o + 128] = cmul_conj(yb[k], wkb);
            wka = cmul(wka, w256);
            wkb = cmul(wkb, w256);
        }
    }
}

// ---------------- movement kernels (16B-vectorized) ----------------
// k_pre: A[n1][n2] = pack(x[n2*2048+n1]); also generates twiddle tables in first 24 blocks.
// grid (N1/64=32, N2/32=128), block (32,8)
__global__ __launch_bounds__(256) void k_pre(const float* __restrict__ x, float2* __restrict__ A,
                                             float2* T1, float2* T2) {
    __shared__ float tile[64][33];     // [n1-in-tile][n2-in-tile]
    int c0 = blockIdx.x * 64;   // n1 base
    int r0 = blockIdx.y * 32;   // n2 base
    int tx = threadIdx.x, ty = threadIdx.y;
    if (blockIdx.y == 0 && blockIdx.x < 24) {
        int j = blockIdx.x * 256 + ty * 32 + tx;
        if (j < 4096) {
            double ang = -2.0 * M_PI * (double)j / 4096.0;
            T1[j] = make_float2((float)cos(ang), (float)sin(ang));
        } else if (j < 4096 + 2048) {
            int b = j - 4096;
            double ang = -2.0 * M_PI * (double)b / 8388608.0;
            T2[b] = make_float2((float)cos(ang), (float)sin(ang));
        }
    }
    #pragma unroll
    for (int j = 0; j < 4; ++j) {
        int row = ty + 8*j;
        float2 v = *(const float2*)(x + (size_t)(r0 + row) * N1 + c0 + 2*tx);
        tile[2*tx][row]   = v.x;
        tile[2*tx+1][row] = v.y;
    }
    __syncthreads();
    int i  = tx & 15;
    int cb = (tx >> 4) + 2*ty;
    #pragma unroll
    for (int jj = 0; jj < 4; ++jj) {
        int c = cb + 16*jj;
        float v0 = tile[c][2*i], v1 = tile[c][2*i+1];
        float4 o = make_float4(fmaxf(v0, 0.f), fmaxf(-v0, 0.f), fmaxf(v1, 0.f), fmaxf(-v1, 0.f));
        *(float4*)(A + (size_t)(c0 + c) * N2 + r0 + 2*i) = o;
    }
}

// k_trans: out[c][r] = in[r][c]; grid (inCols/64, inRows/32), block (32,8), float4 both sides
__global__ __launch_bounds__(256) void k_trans(const float2* __restrict__ in, float2* __restrict__ out,
                                               int inCols, int inRows) {
    __shared__ float2 tile[32][65];
    int c0 = blockIdx.x * 64;
    int r0 = blockIdx.y * 32;
    int tx = threadIdx.x, ty = threadIdx.y;
    #pragma unroll
    for (int j = 0; j < 4; ++j) {
        int row = ty + 8*j;
        float4 v = *(const float4*)(in + (size_t)(r0 + row) * inCols + c0 + 2*tx);
        tile[row][2*tx]   = make_float2(v.x, v.y);
        tile[row][2*tx+1] = make_float2(v.z, v.w);
    }
    __syncthreads();
    int i  = tx & 15;
    int cb = (tx >> 4) + 2*ty;
    #pragma unroll
    for (int jj = 0; jj < 4; ++jj) {
        int c = cb + 16*jj;
        float2 a = tile[2*i][c], b = tile[2*i+1][c];
        *(float4*)(out + (size_t)(c0 + c) * inRows + r0 + 2*i) = make_float4(a.x, a.y, b.x, b.y);
    }
}

// k_post: final transpose + envelope epilogue + deterministic std partials.
// grid (N2/64=64, N1/32=64), block (32,8)
__global__ __launch_bounds__(256) void k_post(const float2* __restrict__ A, const float* __restrict__ x,
                                              float* __restrict__ out, float* __restrict__ part) {
    __shared__ float2 tile[32][65];    // [n1-in-tile][n2-in-tile]
    __shared__ float red[2][8][32];
    int c0 = blockIdx.x * 64;   // n2 base
    int r0 = blockIdx.y * 32;   // n1 base
    int tx = threadIdx.x, ty = threadIdx.y;
    #pragma unroll
    for (int j = 0; j < 4; ++j) {
        int row = ty + 8*j;            // n1 index in tile
        float4 v = *(const float4*)(A + (size_t)(r0 + row) * N2 + c0 + 2*tx);
        tile[row][2*tx]   = make_float2(v.x, v.y);
        tile[row][2*tx+1] = make_float2(v.z, v.w);
    }
    __syncthreads();
    float s1 = 0.f, s2 = 0.f;
    #pragma unroll
    for (int jj = 0; jj < 8; ++jj) {
        int cc = ty + 8*jj;            // n2 index in tile, 0..63
        int n2 = c0 + cc;
        size_t n = (size_t)n2 * N1 + r0 + tx;
        float2 w = tile[tx][cc];
        float xv = x[n];
        float up = fmaxf(xv, 0.f);
        float dn = fmaxf(-xv, 0.f);
        float hu = w.y - dn;          // H(up)
        float hd = up - w.x;          // H(down)
        float em = sqrtf(up*up + hu*hu);
        float en = sqrtf(dn*dn + hd*hd);
        float avg = 0.5f * (em - en);
        float imf = xv - avg;
        out[NTOT + n] = avg;
        s1 += imf;
        s2 += imf * imf;
    }
    red[0][ty][tx] = s1;
    red[1][ty][tx] = s2;
    __syncthreads();
    if (ty == 0) {
        #pragma unroll
        for (int e = 1; e < 8; ++e) { s1 += red[0][e][tx]; s2 += red[1][e][tx]; }
        int slot = blockIdx.y * 64 + blockIdx.x;    // 64*64 = 4096 slots
        part[slot * 32 + tx]          = s1;         // d = (blockIdx.y&1)*32 + tx
        part[131072 + slot * 32 + tx] = s2;
    }
}

// std over L (ddof=1) from k_post partials. g = b*64 + d, 2048 threads.
__global__ __launch_bounds__(256) void std_final(const float* __restrict__ part, float* __restrict__ scalev) {
    int g = blockIdx.x * 256 + threadIdx.x;
    int b = g >> 6, d = g & 63;
    int dh = d >> 5, dl = d & 31;
    float s1 = 0.f, s2 = 0.f;
    for (int q = 0; q < 32; ++q) {
        int by = 2*q + dh;
        #pragma unroll
        for (int e = 0; e < 2; ++e) {
            int slot = by * 64 + 2*b + e;
            s1 += part[slot * 32 + dl];
            s2 += part[131072 + slot * 32 + dl];
        }
    }
    float mean = s1 / (float)LL;
    float var  = (s2 - (float)LL * mean * mean) / (float)(LL - 1);
    var = fmaxf(var, 0.f);
    scalev[g] = 1.f / (sqrtf(var) + 0.01f);
}

// imf = (x - avg) * scale
__global__ __launch_bounds__(256) void imf_final(const float* __restrict__ x, float* __restrict__ out,
                                                 const float* __restrict__ scalev) {
    size_t i = ((size_t)blockIdx.x * 256 + threadIdx.x) * 4;
    float4 xv = *(const float4*)(x + i);
    float4 av = *(const float4*)(out + NTOT + i);
    int b = (int)(i >> 18);          // L*D = 2^18
    int d = (int)(i & 63);
    const float* sc = scalev + b * 64;
    float4 v;
    v.x = (xv.x - av.x) * sc[d];
    v.y = (xv.y - av.y) * sc[d + 1];
    v.z = (xv.z - av.z) * sc[d + 2];
    v.w = (xv.w - av.w) * sc[d + 3];
    *(float4*)(out + i) = v;
}

// ---------------- launch ----------------
extern "C" void kernel_launch(void* const* d_in, const int* in_sizes, int n_in,
                              void* d_out, int out_size, void* d_ws, size_t ws_size,
                              hipStream_t stream) {
    const float* x = (const float*)d_in[0];
    float* out = (float*)d_out;
    char* w = (char*)d_ws;

    float2* T1     = (float2*)w;                   // 32 KB
    float2* T2     = (float2*)(w + 32 * 1024);     // 16 KB
    float*  scalev = (float*)(w + 48 * 1024);      // 8 KB
    float2* A      = (float2*)(w + (1 << 20));     // 64 MB scratch
    float2* Bbuf   = (float2*)d_out;               // d_out doubles as 2nd 64 MB buffer
    float*  part   = (float*)d_out;                // 1 MB partials in imf region (free until imf_final)

    hipLaunchKernelGGL(k_pre, dim3(N1/64, N2/32), dim3(32, 8), 0, stream, x, A, T1, T2);
    hipLaunchKernelGGL((fft4096<false, M_TW>), dim3(N1), dim3(256), 0, stream, A, T1, T2);
    hipLaunchKernelGGL(k_trans, dim3(N2/64, N1/32), dim3(32, 8), 0, stream, A, Bbuf, N2, N1);
    hipLaunchKernelGGL(fftmid, dim3(N2), dim3(128), 0, stream, Bbuf, T1, T2);
    hipLaunchKernelGGL(k_trans, dim3(N1/64, N2/32), dim3(32, 8), 0, stream, Bbuf, A, N1, N2);
    hipLaunchKernelGGL((fft4096<true, M_SCALE>), dim3(N1), dim3(256), 0, stream, A, T1, T2);

    hipLaunchKernelGGL(k_post, dim3(N2/64, N1/32), dim3(32, 8), 0, stream, A, x, out, part);
    hipLaunchKernelGGL(std_final, dim3(8), dim3(256), 0, stream, part, scalev);
    hipLaunchKernelGGL(imf_final, dim3(NTOT / 4 / 256), dim3(256), 0, stream, x, out, scalev);
}

// Round 11
// 188.924 us; speedup vs baseline: 1.4245x; 1.0009x over previous
//
#include <hip/hip_runtime.h>
#include <math.h>

#define NTOT 8388608   // 2^23 = 32*4096*64
#define N1   2048
#define N2   4096
#define BB   32
#define LL   4096
#define DD   64

enum { M_NONE = 0, M_TW = 1, M_SCALE = 4 };

__device__ inline float2 cmul(float2 a, float2 b) {
    return make_float2(a.x*b.x - a.y*b.y, a.x*b.y + a.y*b.x);
}
__device__ inline float2 cmul_conj(float2 a, float2 b) {   // a * conj(b)
    return make_float2(a.x*b.x + a.y*b.y, a.y*b.x - a.x*b.y);
}
__device__ inline float2 cadd(float2 a, float2 b){ return make_float2(a.x+b.x, a.y+b.y); }
__device__ inline float2 csub(float2 a, float2 b){ return make_float2(a.x-b.x, a.y-b.y); }
__device__ inline float2 mul_pi(float2 a){ return make_float2(-a.y, a.x); }   // * i
__device__ inline float2 mul_mi(float2 a){ return make_float2(a.y, -a.x); }   // * -i
__device__ inline int pidx(int a){ return a + (a >> 4); }                     // float2 LDS pad

// DFT8: y_k = sum_m x_m W8^{+-km}
template<bool INV>
__device__ inline void dft8(const float2* x, float2* y) {
    const float C = 0.70710678118654752f;
    float2 t0=cadd(x[0],x[4]), t1=cadd(x[1],x[5]), t2=cadd(x[2],x[6]), t3=cadd(x[3],x[7]);
    float2 u0=csub(x[0],x[4]), u1=csub(x[1],x[5]), u2=csub(x[2],x[6]), u3=csub(x[3],x[7]);
    if (!INV) {
        u1 = make_float2(C*(u1.x+u1.y), C*(u1.y-u1.x));
        u2 = mul_mi(u2);
        u3 = make_float2(C*(u3.y-u3.x), -C*(u3.x+u3.y));
    } else {
        u1 = make_float2(C*(u1.x-u1.y), C*(u1.y+u1.x));
        u2 = mul_pi(u2);
        u3 = make_float2(-C*(u3.x+u3.y), C*(u3.x-u3.y));
    }
    {
        float2 s0=cadd(t0,t2), s1=cadd(t1,t3), d0=csub(t0,t2);
        float2 d1 = INV ? mul_pi(csub(t1,t3)) : mul_mi(csub(t1,t3));
        y[0]=cadd(s0,s1); y[4]=csub(s0,s1); y[2]=cadd(d0,d1); y[6]=csub(d0,d1);
    }
    {
        float2 s0=cadd(u0,u2), s1=cadd(u1,u3), d0=csub(u0,u2);
        float2 d1 = INV ? mul_pi(csub(u1,u3)) : mul_mi(csub(u1,u3));
        y[1]=cadd(s0,s1); y[5]=csub(s0,s1); y[3]=cadd(d0,d1); y[7]=csub(d0,d1);
    }
}

// DFT16 = split into even/odd DFT8 + W16^k combine
template<bool INV>
__device__ inline void dft16(const float2* x, float2* y) {
    const float C  = 0.70710678118654752f;
    const float c1 = 0.92387953251128674f;   // cos(pi/8)
    const float s1 = 0.38268343236508977f;   // sin(pi/8)
    float2 e[8], o[8], E[8], O[8];
    #pragma unroll
    for (int m = 0; m < 8; ++m) { e[m] = x[2*m]; o[m] = x[2*m+1]; }
    dft8<INV>(e, E);
    dft8<INV>(o, O);
    O[1] = cmul(O[1], make_float2( c1, INV ?  s1 : -s1));
    O[2] = cmul(O[2], make_float2(  C, INV ?   C : -C ));
    O[3] = cmul(O[3], make_float2( s1, INV ?  c1 : -c1));
    O[4] = INV ? mul_pi(O[4]) : mul_mi(O[4]);
    O[5] = cmul(O[5], make_float2(-s1, INV ?  c1 : -c1));
    O[6] = cmul(O[6], make_float2( -C, INV ?   C : -C ));
    O[7] = cmul(O[7], make_float2(-c1, INV ?  s1 : -s1));
    #pragma unroll
    for (int k = 0; k < 8; ++k) {
        y[k]     = cadd(E[k], O[k]);
        y[k + 8] = csub(E[k], O[k]);
    }
}

// inverse DFT8 with x[4..7] == 0
__device__ inline void dft8_h0_inv(const float2* x, float2* y) {
    const float C = 0.70710678118654752f;
    float2 u1 = make_float2(C*(x[1].x - x[1].y), C*(x[1].y + x[1].x));
    float2 u2 = mul_pi(x[2]);
    float2 u3 = make_float2(-C*(x[3].x + x[3].y), C*(x[3].x - x[3].y));
    {
        float2 s0=cadd(x[0],x[2]), s1=cadd(x[1],x[3]), d0=csub(x[0],x[2]);
        float2 d1 = mul_pi(csub(x[1],x[3]));
        y[0]=cadd(s0,s1); y[4]=csub(s0,s1); y[2]=cadd(d0,d1); y[6]=csub(d0,d1);
    }
    {
        float2 s0=cadd(x[0],u2), s1=cadd(u1,u3), d0=csub(x[0],u2);
        float2 d1 = mul_pi(csub(u1,u3));
        y[1]=cadd(s0,s1); y[5]=csub(s0,s1); y[3]=cadd(d0,d1); y[7]=csub(d0,d1);
    }
}

// inverse DFT16 with x[8..15] == 0 (only x[0..7] passed)
__device__ inline void dft16_h0_inv(const float2* x, float2* y) {
    const float C  = 0.70710678118654752f;
    const float c1 = 0.92387953251128674f;
    const float s1 = 0.38268343236508977f;
    float2 e4[4] = { x[0], x[2], x[4], x[6] };
    float2 o4[4] = { x[1], x[3], x[5], x[7] };
    float2 E[8], O[8];
    dft8_h0_inv(e4, E);
    dft8_h0_inv(o4, O);
    O[1] = cmul(O[1], make_float2( c1,  s1));
    O[2] = cmul(O[2], make_float2(  C,   C));
    O[3] = cmul(O[3], make_float2( s1,  c1));
    O[4] = mul_pi(O[4]);
    O[5] = cmul(O[5], make_float2(-s1,  c1));
    O[6] = cmul(O[6], make_float2( -C,   C));
    O[7] = cmul(O[7], make_float2(-c1,  s1));
    #pragma unroll
    for (int k = 0; k < 8; ++k) {
        y[k]     = cadd(E[k], O[k]);
        y[k + 8] = csub(E[k], O[k]);
    }
}

// y_k *= W^{+-ps*k}, k=1..15 (SH=0: N=4096, SH=1: N=2048)
template<bool INV, int SH>
__device__ inline void twiddle16(float2* y, int ps, const float2* __restrict__ T1t) {
    float2 w[16];
    w[1] = T1t[(ps << SH) & 4095];
    w[2] = cmul(w[1], w[1]);
    w[3] = cmul(w[2], w[1]);
    w[4] = cmul(w[2], w[2]);
    w[5] = cmul(w[4], w[1]);
    w[6] = cmul(w[3], w[3]);
    w[7] = cmul(w[4], w[3]);
    w[8] = cmul(w[4], w[4]);
    w[9] = cmul(w[8], w[1]);
    w[10]= cmul(w[5], w[5]);
    w[11]= cmul(w[8], w[3]);
    w[12]= cmul(w[6], w[6]);
    w[13]= cmul(w[8], w[5]);
    w[14]= cmul(w[7], w[7]);
    w[15]= cmul(w[8], w[7]);
    #pragma unroll
    for (int k = 1; k < 16; ++k)
        y[k] = INV ? cmul_conj(y[k], w[k]) : cmul(y[k], w[k]);
}

// W_2^23^{t} from split tables (t < 2^23)
__device__ inline float2 wbig(int t, const float2* __restrict__ T1t, const float2* __restrict__ T2t) {
    return cmul(T1t[t >> 11], T2t[t & 2047]);
}

// ---------------- 4096-point radix-16 Stockham (16^3), 256 threads, one row per block ----------------
template<bool INV, int MODE>
__global__ __launch_bounds__(256, 3) void fft4096(float2* data,
                                                  const float2* __restrict__ T1t,
                                                  const float2* __restrict__ T2t) {
    __shared__ float2 S[4352];
    const int t = threadIdx.x;
    const int r = blockIdx.x;
    float2* base = data + (size_t)r * 4096;

    float2 x[16], y[16];
    #pragma unroll
    for (int m = 0; m < 16; ++m) x[m] = base[t + 256*m];

    dft16<INV>(x, y);
    twiddle16<INV, 0>(y, t, T1t);
    #pragma unroll
    for (int k = 0; k < 16; ++k) S[pidx(16*t + k)] = y[k];
    __syncthreads();
    #pragma unroll
    for (int m = 0; m < 16; ++m) x[m] = S[pidx(t + 256*m)];

    dft16<INV>(x, y);
    {
        const int q = t & 15, ps = t - q;
        twiddle16<INV, 0>(y, ps, T1t);
        __syncthreads();
        #pragma unroll
        for (int k = 0; k < 16; ++k) S[pidx(16*ps + q + 16*k)] = y[k];
    }
    __syncthreads();
    #pragma unroll
    for (int m = 0; m < 16; ++m) x[m] = S[pidx(t + 256*m)];

    dft16<INV>(x, y);

    if (MODE == M_TW) {
        float2 wb    = wbig(r * t, T1t, T2t);
        float2 wstep = wbig(256 * r, T1t, T2t);
        #pragma unroll
        for (int k = 0; k < 16; ++k) {
            int o = t + 256*k;
            base[o] = INV ? cmul_conj(y[k], wb) : cmul(y[k], wb);
            wb = INV ? cmul_conj(wb, wstep) : cmul(wb, wstep);
        }
    } else {
        #pragma unroll
        for (int k = 0; k < 16; ++k) {
            int o = t + 256*k;
            float2 v = y[k];
            if (MODE == M_SCALE) {
                const float sc = 1.f / 8388608.f;
                v.x *= sc; v.y *= sc;
            }
            base[o] = v;
        }
    }
}

// ------- fused middle: fwd 2048 FFT + Hilbert mask + inv 2048 FFT + conj four-step twiddle -------
// Radix-16 (2048 = 16*16*8), 128 threads, one row per block.
__global__ __launch_bounds__(128, 3) void fftmid(float2* data,
                                                 const float2* __restrict__ T1t,
                                                 const float2* __restrict__ T2t) {
    __shared__ float2 S[2176];
    const int t = threadIdx.x;         // 0..127
    const int r = blockIdx.x;          // 0..4095
    float2* base = data + (size_t)r * 2048;

    float2 x[16], y[16];
    #pragma unroll
    for (int m = 0; m < 16; ++m) x[m] = base[t + 128*m];

    // ---- fwd stage 0: radix-16, s=1, ps=t ----
    dft16<false>(x, y);
    twiddle16<false, 1>(y, t, T1t);
    #pragma unroll
    for (int k = 0; k < 16; ++k) S[pidx(16*t + k)] = y[k];
    __syncthreads();
    #pragma unroll
    for (int m = 0; m < 16; ++m) x[m] = S[pidx(t + 128*m)];

    // ---- fwd stage 1: radix-16, s=16 ----
    dft16<false>(x, y);
    {
        const int q = t & 15, ps = t - q;
        twiddle16<false, 1>(y, ps, T1t);
        __syncthreads();
        #pragma unroll
        for (int k = 0; k < 16; ++k) S[pidx(16*ps + q + 16*k)] = y[k];
    }
    __syncthreads();

    // ---- fwd final radix-8 (s=256, ps=0), two butterflies j=t and j=t+128 ----
    float2 xa[8], xb[8], ya[8], yb[8];
    #pragma unroll
    for (int m = 0; m < 8; ++m) {
        xa[m] = S[pidx(t + 256*m)];
        xb[m] = S[pidx(t + 128 + 256*m)];
    }
    dft8<false>(xa, ya);   // positions o = t + 256k
    dft8<false>(xb, yb);   // positions o = t + 128 + 256k
    // ---- Hilbert mask + inv radix-16 stage 0, in registers ----
    {
        float2 z[8];
        float h0 = (t == 0 && r == 0) ? 1.f : 2.f;   // o = t, global k = t*4096+r
        z[0] = make_float2(ya[0].x * h0,  ya[0].y * h0);
        z[1] = make_float2(yb[0].x * 2.f, yb[0].y * 2.f);
        z[2] = make_float2(ya[1].x * 2.f, ya[1].y * 2.f);
        z[3] = make_float2(yb[1].x * 2.f, yb[1].y * 2.f);
        z[4] = make_float2(ya[2].x * 2.f, ya[2].y * 2.f);
        z[5] = make_float2(yb[2].x * 2.f, yb[2].y * 2.f);
        z[6] = make_float2(ya[3].x * 2.f, ya[3].y * 2.f);
        z[7] = make_float2(yb[3].x * 2.f, yb[3].y * 2.f);
        dft16_h0_inv(z, y);
        if (t == 0 && r == 0) {                      // corner o=1024 = ya[4]
            float2 c = ya[4];
            #pragma unroll
            for (int k = 0; k < 16; ++k) {
                if (k & 1) { y[k].x -= c.x; y[k].y -= c.y; }
                else       { y[k].x += c.x; y[k].y += c.y; }
            }
        }
    }
    twiddle16<true, 1>(y, t, T1t);
    __syncthreads();
    #pragma unroll
    for (int k = 0; k < 16; ++k) S[pidx(16*t + k)] = y[k];
    __syncthreads();

    // ---- inv stage 1: radix-16, s=16 ----
    #pragma unroll
    for (int m = 0; m < 16; ++m) x[m] = S[pidx(t + 128*m)];
    dft16<true>(x, y);
    {
        const int q = t & 15, ps = t - q;
        twiddle16<true, 1>(y, ps, T1t);
        __syncthreads();
        #pragma unroll
        for (int k = 0; k < 16; ++k) S[pidx(16*ps + q + 16*k)] = y[k];
    }
    __syncthreads();

    // ---- inv final radix-8 (s=256, ps=0) + conj four-step twiddle + store ----
    #pragma unroll
    for (int m = 0; m < 8; ++m) {
        xa[m] = S[pidx(t + 256*m)];
        xb[m] = S[pidx(t + 128 + 256*m)];
    }
    dft8<true>(xa, ya);
    dft8<true>(xb, yb);
    {
        float2 wka  = wbig(r * t, T1t, T2t);         // per-lane, 2 gathers
        float2 w128 = wbig(128 * r, T1t, T2t);       // uniform
        float2 w256 = cmul(w128, w128);              // uniform
        float2 wkb  = cmul(wka, w128);
        #pragma unroll
        for (int k = 0; k < 8; ++k) {
            int o = t + 256*k;
            base[o]       = cmul_conj(ya[k], wka);
            base[o + 128] = cmul_conj(yb[k], wkb);
            wka = cmul(wka, w256);
            wkb = cmul(wkb, w256);
        }
    }
}

// ---------------- movement kernels (16B-vectorized) ----------------
// k_pre: A[n1][n2] = pack(x[n2*2048+n1]); also generates twiddle tables in first 24 blocks.
// grid (N1/64=32, N2/32=128), block (32,8)
__global__ __launch_bounds__(256) void k_pre(const float* __restrict__ x, float2* __restrict__ A,
                                             float2* T1, float2* T2) {
    __shared__ float tile[64][33];     // [n1-in-tile][n2-in-tile]
    int c0 = blockIdx.x * 64;   // n1 base
    int r0 = blockIdx.y * 32;   // n2 base
    int tx = threadIdx.x, ty = threadIdx.y;
    if (blockIdx.y == 0 && blockIdx.x < 24) {
        int j = blockIdx.x * 256 + ty * 32 + tx;
        if (j < 4096) {
            double ang = -2.0 * M_PI * (double)j / 4096.0;
            T1[j] = make_float2((float)cos(ang), (float)sin(ang));
        } else if (j < 4096 + 2048) {
            int b = j - 4096;
            double ang = -2.0 * M_PI * (double)b / 8388608.0;
            T2[b] = make_float2((float)cos(ang), (float)sin(ang));
        }
    }
    #pragma unroll
    for (int j = 0; j < 4; ++j) {
        int row = ty + 8*j;
        float2 v = *(const float2*)(x + (size_t)(r0 + row) * N1 + c0 + 2*tx);
        tile[2*tx][row]   = v.x;
        tile[2*tx+1][row] = v.y;
    }
    __syncthreads();
    int i  = tx & 15;
    int cb = (tx >> 4) + 2*ty;
    #pragma unroll
    for (int jj = 0; jj < 4; ++jj) {
        int c = cb + 16*jj;
        float v0 = tile[c][2*i], v1 = tile[c][2*i+1];
        float4 o = make_float4(fmaxf(v0, 0.f), fmaxf(-v0, 0.f), fmaxf(v1, 0.f), fmaxf(-v1, 0.f));
        *(float4*)(A + (size_t)(c0 + c) * N2 + r0 + 2*i) = o;
    }
}

// k_trans: out[c][r] = in[r][c]; grid (inCols/64, inRows/32), block (32,8), float4 both sides
__global__ __launch_bounds__(256) void k_trans(const float2* __restrict__ in, float2* __restrict__ out,
                                               int inCols, int inRows) {
    __shared__ float2 tile[32][65];
    int c0 = blockIdx.x * 64;
    int r0 = blockIdx.y * 32;
    int tx = threadIdx.x, ty = threadIdx.y;
    #pragma unroll
    for (int j = 0; j < 4; ++j) {
        int row = ty + 8*j;
        float4 v = *(const float4*)(in + (size_t)(r0 + row) * inCols + c0 + 2*tx);
        tile[row][2*tx]   = make_float2(v.x, v.y);
        tile[row][2*tx+1] = make_float2(v.z, v.w);
    }
    __syncthreads();
    int i  = tx & 15;
    int cb = (tx >> 4) + 2*ty;
    #pragma unroll
    for (int jj = 0; jj < 4; ++jj) {
        int c = cb + 16*jj;
        float2 a = tile[2*i][c], b = tile[2*i+1][c];
        *(float4*)(out + (size_t)(c0 + c) * inRows + r0 + 2*i) = make_float4(a.x, a.y, b.x, b.y);
    }
}

// k_post: final transpose + envelope epilogue + deterministic std partials.
// grid (N2/64=64, N1/32=64), block (32,8)
__global__ __launch_bounds__(256) void k_post(const float2* __restrict__ A, const float* __restrict__ x,
                                              float* __restrict__ out, float* __restrict__ part) {
    __shared__ float2 tile[32][65];    // [n1-in-tile][n2-in-tile]
    __shared__ float red[2][8][32];
    int c0 = blockIdx.x * 64;   // n2 base
    int r0 = blockIdx.y * 32;   // n1 base
    int tx = threadIdx.x, ty = threadIdx.y;
    #pragma unroll
    for (int j = 0; j < 4; ++j) {
        int row = ty + 8*j;            // n1 index in tile
        float4 v = *(const float4*)(A + (size_t)(r0 + row) * N2 + c0 + 2*tx);
        tile[row][2*tx]   = make_float2(v.x, v.y);
        tile[row][2*tx+1] = make_float2(v.z, v.w);
    }
    __syncthreads();
    float s1 = 0.f, s2 = 0.f;
    #pragma unroll
    for (int jj = 0; jj < 8; ++jj) {
        int cc = ty + 8*jj;            // n2 index in tile, 0..63
        int n2 = c0 + cc;
        size_t n = (size_t)n2 * N1 + r0 + tx;
        float2 w = tile[tx][cc];
        float xv = x[n];
        float up = fmaxf(xv, 0.f);
        float dn = fmaxf(-xv, 0.f);
        float hu = w.y - dn;          // H(up)
        float hd = up - w.x;          // H(down)
        float em = sqrtf(up*up + hu*hu);
        float en = sqrtf(dn*dn + hd*hd);
        float avg = 0.5f * (em - en);
        float imf = xv - avg;
        out[NTOT + n] = avg;
        s1 += imf;
        s2 += imf * imf;
    }
    red[0][ty][tx] = s1;
    red[1][ty][tx] = s2;
    __syncthreads();
    if (ty == 0) {
        #pragma unroll
        for (int e = 1; e < 8; ++e) { s1 += red[0][e][tx]; s2 += red[1][e][tx]; }
        int slot = blockIdx.y * 64 + blockIdx.x;    // 64*64 = 4096 slots
        part[slot * 32 + tx]          = s1;         // d = (blockIdx.y&1)*32 + tx
        part[131072 + slot * 32 + tx] = s2;
    }
}

// std over L (ddof=1) from k_post partials. g = b*64 + d, 2048 threads.
__global__ __launch_bounds__(256) void std_final(const float* __restrict__ part, float* __restrict__ scalev) {
    int g = blockIdx.x * 256 + threadIdx.x;
    int b = g >> 6, d = g & 63;
    int dh = d >> 5, dl = d & 31;
    float s1 = 0.f, s2 = 0.f;
    for (int q = 0; q < 32; ++q) {
        int by = 2*q + dh;
        #pragma unroll
        for (int e = 0; e < 2; ++e) {
            int slot = by * 64 + 2*b + e;
            s1 += part[slot * 32 + dl];
            s2 += part[131072 + slot * 32 + dl];
        }
    }
    float mean = s1 / (float)LL;
    float var  = (s2 - (float)LL * mean * mean) / (float)(LL - 1);
    var = fmaxf(var, 0.f);
    scalev[g] = 1.f / (sqrtf(var) + 0.01f);
}

// imf = (x - avg) * scale
__global__ __launch_bounds__(256) void imf_final(const float* __restrict__ x, float* __restrict__ out,
                                                 const float* __restrict__ scalev) {
    size_t i = ((size_t)blockIdx.x * 256 + threadIdx.x) * 4;
    float4 xv = *(const float4*)(x + i);
    float4 av = *(const float4*)(out + NTOT + i);
    int b = (int)(i >> 18);          // L*D = 2^18
    int d = (int)(i & 63);
    const float* sc = scalev + b * 64;
    float4 v;
    v.x = (xv.x - av.x) * sc[d];
    v.y = (xv.y - av.y) * sc[d + 1];
    v.z = (xv.z - av.z) * sc[d + 2];
    v.w = (xv.w - av.w) * sc[d + 3];
    *(float4*)(out + i) = v;
}

// ---------------- launch ----------------
extern "C" void kernel_launch(void* const* d_in, const int* in_sizes, int n_in,
                              void* d_out, int out_size, void* d_ws, size_t ws_size,
                              hipStream_t stream) {
    const float* x = (const float*)d_in[0];
    float* out = (float*)d_out;
    char* w = (char*)d_ws;

    float2* T1     = (float2*)w;                   // 32 KB
    float2* T2     = (float2*)(w + 32 * 1024);     // 16 KB
    float*  scalev = (float*)(w + 48 * 1024);      // 8 KB
    float2* A      = (float2*)(w + (1 << 20));     // 64 MB scratch
    float2* Bbuf   = (float2*)d_out;               // d_out doubles as 2nd 64 MB buffer
    float*  part   = (float*)d_out;                // 1 MB partials in imf region (free until imf_final)

    hipLaunchKernelGGL(k_pre, dim3(N1/64, N2/32), dim3(32, 8), 0, stream, x, A, T1, T2);
    hipLaunchKernelGGL((fft4096<false, M_TW>), dim3(N1), dim3(256), 0, stream, A, T1, T2);
    hipLaunchKernelGGL(k_trans, dim3(N2/64, N1/32), dim3(32, 8), 0, stream, A, Bbuf, N2, N1);
    hipLaunchKernelGGL(fftmid, dim3(N2), dim3(128), 0, stream, Bbuf, T1, T2);
    hipLaunchKernelGGL(k_trans, dim3(N1/64, N2/32), dim3(32, 8), 0, stream, Bbuf, A, N1, N2);
    hipLaunchKernelGGL((fft4096<true, M_SCALE>), dim3(N1), dim3(256), 0, stream, A, T1, T2);

    hipLaunchKernelGGL(k_post, dim3(N2/64, N1/32), dim3(32, 8), 0, stream, A, x, out, part);
    hipLaunchKernelGGL(std_final, dim3(8), dim3(256), 0, stream, part, scalev);
    hipLaunchKernelGGL(imf_final, dim3(NTOT / 4 / 256), dim3(256), 0, stream, x, out, scalev);
}